// Round 5
// baseline (169.441 us; speedup 1.0000x reference)
//
#include <hip/hip_runtime.h>
#include <hip/hip_bf16.h>
#include <math.h>

#define BB 8
#define NN 1024
#define F_IN 384
#define F_HID 96
#define HEADS 8
#define F_OUT 384
#define ROWS (BB*NN)                 // 8192
#define H_DIM 1152                   // HEADS*F_HID + F_IN
#define OUT_DIM 1536                 // F_OUT + H_DIM
#define NEG 0.01f
#define LN_EPS 1e-5f
#define LOG2E 1.4426950408889634f

typedef __bf16 bf16x8 __attribute__((ext_vector_type(8)));
typedef float  f32x4  __attribute__((ext_vector_type(4)));

static __device__ __forceinline__ unsigned short b16u(float x) {
    union { __bf16 h; unsigned short u; } c; c.h = (__bf16)x; return c.u;
}

typedef __attribute__((address_space(1))) const unsigned char g1_t;
typedef __attribute__((address_space(3))) unsigned char l3_t;
static __device__ __forceinline__ void gl16(const void* g, void* l) {
    __builtin_amdgcn_global_load_lds((g1_t*)g, (l3_t*)l, 16, 0, 0);
}

// ---------------- kW: WmT[n][k] = bf16(Wm[k][n]) ----------------
__global__ __launch_bounds__(256) void kW(const float* __restrict__ Wm,
                                          unsigned short* __restrict__ WmT) {
    __shared__ float tile[32][33];
    const int t = threadIdx.x;
    const int k0 = (blockIdx.x / 12) * 32, n0 = (blockIdx.x % 12) * 32;
#pragma unroll
    for (int p = 0; p < 4; ++p) {
        const int e = t + 256*p, kk = e >> 5, nn = e & 31;
        tile[kk][nn] = Wm[(size_t)(k0 + kk) * F_OUT + n0 + nn];
    }
    __syncthreads();
#pragma unroll
    for (int p = 0; p < 4; ++p) {
        const int e = t + 256*p, nn = e >> 5, kk = e & 31;
        WmT[(size_t)(n0 + nn) * H_DIM + k0 + kk] = b16u(tile[kk][nn]);
    }
}

// ---------------- kA: LN(X) -> V -> VT bf16, Q, K (unchanged) ----------------
__global__ __launch_bounds__(256) void kA(const float* __restrict__ X,
                                          const float* __restrict__ Wv, const float* __restrict__ bv,
                                          const float* __restrict__ Wq, const float* __restrict__ bq,
                                          const float* __restrict__ Wk, const float* __restrict__ bk,
                                          unsigned short* __restrict__ VT,
                                          float* __restrict__ Qw, float* __restrict__ Kw) {
    __shared__ float xn[8][F_IN];
    __shared__ float vsh[8][F_HID];
    const int t = threadIdx.x, r = t >> 5, lane = t & 31;
    const int row0 = blockIdx.x * 8, row = row0 + r;
    const int b = row0 >> 10, i_in = row0 & 1023;

    const float4* xrow = (const float4*)(X + (size_t)row * F_IN);
    float4 xv[3];
    float s = 0.f, sq = 0.f;
#pragma unroll
    for (int k = 0; k < 3; ++k) {
        xv[k] = xrow[lane + 32*k];
        s  += xv[k].x + xv[k].y + xv[k].z + xv[k].w;
        sq += xv[k].x*xv[k].x + xv[k].y*xv[k].y + xv[k].z*xv[k].z + xv[k].w*xv[k].w;
    }
#pragma unroll
    for (int m = 1; m < 32; m <<= 1) { s += __shfl_xor(s, m); sq += __shfl_xor(sq, m); }
    const float mu  = s * (1.f/F_IN);
    const float var = sq * (1.f/F_IN) - mu*mu;
    const float rstd = rsqrtf(var + LN_EPS);
    float4* xnr = (float4*)xn[r];
#pragma unroll
    for (int k = 0; k < 3; ++k) {
        float4 o;
        o.x = (xv[k].x - mu) * rstd; o.y = (xv[k].y - mu) * rstd;
        o.z = (xv[k].z - mu) * rstd; o.w = (xv[k].w - mu) * rstd;
        xnr[lane + 32*k] = o;
    }
    __syncthreads();

    float acc[3];
#pragma unroll
    for (int c = 0; c < 3; ++c) acc[c] = bv[lane + 32*c];
    for (int f = 0; f < F_IN; ++f) {
        const float xvv = xn[r][f];
        const float* wrow = Wv + (size_t)f * F_HID + lane;
#pragma unroll
        for (int c = 0; c < 3; ++c) acc[c] = fmaf(xvv, wrow[32*c], acc[c]);
    }
#pragma unroll
    for (int c = 0; c < 3; ++c) vsh[r][lane + 32*c] = acc[c];
    __syncthreads();

#pragma unroll
    for (int p = 0; p < 3; ++p) {
        const int e = t + 256*p, f = e >> 3, ii = e & 7;
        VT[((size_t)b * F_HID + f) * NN + i_in + ii] = b16u(vsh[ii][f]);
    }

    if (t < 128) {
        const int rr = (t >> 3) & 7, h = t & 7;
        const bool isQ = (t < 64);
        const float* Wx = isQ ? Wq : Wk;
        float a = isQ ? bq[h] : bk[h];
#pragma unroll 8
        for (int j = 0; j < F_HID; ++j) a = fmaf(vsh[rr][j], Wx[j*HEADS + h], a);
        const size_t rowx = row0 + rr;
        if (isQ) Qw[rowx * HEADS + h] = a;
        else     Kw[rowx * HEADS + h] = a;
    }
}

// ---------------- kB: 8-wave MFMA attention, B-frags direct from L1/L2 ----------------
// 512 threads = 8 waves; wave w = head w; 16 i-rows/block; chunk = 64 j
// ONE barrier per chunk; Wt double-buffered; no V LDS staging (VT is L1/L2-resident)
__global__ __launch_bounds__(512, 4) void kB(const float* __restrict__ X,
                                             const unsigned short* __restrict__ VT,
                                             const float* __restrict__ Qw,
                                             const float* __restrict__ Kw,
                                             float* __restrict__ out,
                                             unsigned short* __restrict__ Hn) {
    __shared__ float q_sh[16][8];                                  // 512 B
    __shared__ float k_sh[2][64][9];                               // 4.5 KB (pad 9)
    __shared__ __align__(16) unsigned short Wt[2][HEADS][16][64];  // 32 KB (dbuf, swizzled)
    __shared__ float lnS[8][16], lnQ2[8][16];
    __shared__ float sxS[16], sx2S[16];
    __shared__ float mu_sh[16], rs_sh[16];

    const int t = threadIdx.x;
    const int bid = (int)blockIdx.x;
    const int swz = (bid & 7) * 64 + (bid >> 3);   // bijective XCD swizzle (512%8==0)
    const int b  = swz >> 6;
    const int i0 = (swz & 63) * 16;
    const int w = t >> 6, l = t & 63, m = l & 15, g = l >> 4;
    const int si = t >> 5, sj = t & 31;            // softmax: row si, j-pair {2sj,2sj+1}

    const size_t vtbase = (size_t)b * F_HID * NN;
    const size_t krow   = (size_t)b * NN;

    if (t < 128) ((float*)q_sh)[t] = Qw[((size_t)(b*NN + i0)) * HEADS + t];
    k_sh[0][t >> 3][t & 7] = Kw[(krow + (t >> 3)) * HEADS + (t & 7)];
    __syncthreads();

    float q[8];
#pragma unroll
    for (int h = 0; h < 8; ++h) q[h] = q_sh[si][h] * LOG2E;   // fold log2e (lrelu commutes)

    unsigned int* WtU = (unsigned int*)Wt;

    // cooperative head-softmax for pairs (si, 2sj) and (si, 2sj+1) -> Wt[db]
#define SMAX(kb, db)                                                                   \
    {                                                                                  \
        const float* kr0 = k_sh[kb][2*sj];                                             \
        float wE[8], wO[8];                                                            \
        float sE = 0.f, sO = 0.f;                                                      \
        _Pragma("unroll")                                                              \
        for (int h = 0; h < 8; ++h) {                                                  \
            float a0 = q[h] * kr0[h];   a0 = fmaxf(a0, NEG*a0);                        \
            float a1 = q[h] * kr0[9+h]; a1 = fmaxf(a1, NEG*a1);                        \
            wE[h] = __builtin_amdgcn_exp2f(a0); sE += wE[h];                           \
            wO[h] = __builtin_amdgcn_exp2f(a1); sO += wO[h];                           \
        }                                                                              \
        const float iE = __builtin_amdgcn_rcpf(sE);                                    \
        const float iO = __builtin_amdgcn_rcpf(sO);                                    \
        const int wb = (db)*4096 + si*32 + (sj ^ ((si & 7) << 2));                     \
        _Pragma("unroll")                                                              \
        for (int h = 0; h < 8; ++h)                                                    \
            WtU[wb + h*512] = (unsigned int)b16u(wE[h]*iE)                             \
                            | ((unsigned int)b16u(wO[h]*iO) << 16);                    \
    }

    // prologue: softmax(0), stage K(1)
    SMAX(0, 0);
    k_sh[1][t >> 3][t & 7] = Kw[(krow + 64 + (t >> 3)) * HEADS + (t & 7)];
    __syncthreads();

    const f32x4 z4 = {0.f, 0.f, 0.f, 0.f};
    f32x4 acc[6];
#pragma unroll
    for (int fb = 0; fb < 6; ++fb) acc[fb] = z4;

    for (int c = 0; c < 16; ++c) {
        const int cur = c & 1, nxt = cur ^ 1;
        const int j0 = c * 64;

        // B-fragments direct from global (L1-resident V tile), issued early
        bf16x8 bfr[2][6];
#pragma unroll
        for (int kh = 0; kh < 2; ++kh)
#pragma unroll
            for (int fb = 0; fb < 6; ++fb)
                bfr[kh][fb] = *(const bf16x8*)(VT + vtbase + (size_t)(fb*16 + m)*NN
                                               + j0 + kh*32 + g*8);

        // softmax(c+1) under the loads; K(c+2) prefetch
        if (c < 15) {
            SMAX(nxt, nxt);
            if (c < 14)
                k_sh[cur][t >> 3][t & 7] =
                    Kw[(krow + (size_t)(c + 2)*64 + (t >> 3)) * HEADS + (t & 7)];
        }

        // MFMA: head w, A = Wt[cur][w] (16i x 64j), B = bfr
        bf16x8 af[2];
#pragma unroll
        for (int kh = 0; kh < 2; ++kh)
            af[kh] = *(const bf16x8*)((const char*)Wt + cur*16384 + w*2048 + m*128
                                      + ((kh*64 + g*16) ^ ((m & 7) << 4)));
#pragma unroll
        for (int kh = 0; kh < 2; ++kh)
#pragma unroll
            for (int fb = 0; fb < 6; ++fb)
                acc[fb] = __builtin_amdgcn_mfma_f32_16x16x32_bf16(af[kh], bfr[kh][fb],
                                                                  acc[fb], 0, 0, 0);
        __syncthreads();   // Wt[nxt]/k_sh writes visible; Wt[cur] reads retired
    }
#undef SMAX

    // ---- fused LN(H): per-row sums from accs ----
    float s[4] = {0,0,0,0}, s2[4] = {0,0,0,0};
#pragma unroll
    for (int fb = 0; fb < 6; ++fb)
#pragma unroll
        for (int r = 0; r < 4; ++r) {
            const float v = acc[fb][r];
            s[r] += v; s2[r] += v*v;
        }
#pragma unroll
    for (int msk = 1; msk < 16; msk <<= 1)
#pragma unroll
        for (int r = 0; r < 4; ++r) {
            s[r]  += __shfl_xor(s[r],  msk);
            s2[r] += __shfl_xor(s2[r], msk);
        }
    if (m == 0) {
#pragma unroll
        for (int r = 0; r < 4; ++r) { lnS[w][g*4+r] = s[r]; lnQ2[w][g*4+r] = s2[r]; }
    }

    // X phase: 16 rows x 32 lanes, 3 float4 each
    const int rX = t >> 5, lX = t & 31;
    const size_t xrow = (size_t)(b*NN + i0 + rX);
    const float4* x4 = (const float4*)(X + xrow * F_IN);
    float4 xs[3];
    float sx = 0.f, sx2 = 0.f;
#pragma unroll
    for (int kk = 0; kk < 3; ++kk) {
        xs[kk] = x4[lX + 32*kk];
        sx  += xs[kk].x + xs[kk].y + xs[kk].z + xs[kk].w;
        sx2 += xs[kk].x*xs[kk].x + xs[kk].y*xs[kk].y + xs[kk].z*xs[kk].z + xs[kk].w*xs[kk].w;
    }
#pragma unroll
    for (int msk = 1; msk < 32; msk <<= 1) { sx += __shfl_xor(sx, msk); sx2 += __shfl_xor(sx2, msk); }
    if (lX == 0) { sxS[rX] = sx; sx2S[rX] = sx2; }
    __syncthreads();

    if (t < 16) {
        float tot = sxS[t], tot2 = sx2S[t];
#pragma unroll
        for (int ww = 0; ww < 8; ++ww) { tot += lnS[ww][t]; tot2 += lnQ2[ww][t]; }
        const float muh = tot * (1.f/H_DIM);
        const float varh = tot2 * (1.f/H_DIM) - muh*muh;
        mu_sh[t] = muh; rs_sh[t] = rsqrtf(varh + LN_EPS);
    }
    __syncthreads();

    // Hh: fp32 to out cols [384..1152), bf16-normalized to Hn cols [0..768)
#pragma unroll
    for (int r = 0; r < 4; ++r) {
        const int row = g*4 + r;
        const size_t orow = (size_t)(b*NN + i0 + row);
        const float muh = mu_sh[row], rs = rs_sh[row];
#pragma unroll
        for (int fb = 0; fb < 6; ++fb) {
            const int col = w*F_HID + fb*16 + m;
            const float v = acc[fb][r];
            out[orow * OUT_DIM + F_OUT + col] = v;
            Hn[orow * H_DIM + col] = b16u((v - muh) * rs);
        }
    }
    // X: fp32 passthrough to out cols [1152..1536), bf16-normalized to Hn cols [768..1152)
    {
        const float muh = mu_sh[rX], rs = rs_sh[rX];
        float4* oX = (float4*)(out + xrow * OUT_DIM + F_OUT + HEADS*F_HID);
#pragma unroll
        for (int kk = 0; kk < 3; ++kk) {
            oX[lX + 32*kk] = xs[kk];
            ushort4 hh;
            hh.x = b16u((xs[kk].x - muh) * rs);
            hh.y = b16u((xs[kk].y - muh) * rs);
            hh.z = b16u((xs[kk].z - muh) * rs);
            hh.w = b16u((xs[kk].w - muh) * rs);
            *(ushort4*)&Hn[xrow * H_DIM + HEADS*F_HID + 4*(lX + 32*kk)] = hh;
        }
    }
}

// ---------------- kC: O = lrelu(Hn @ WmT^T + bm), tiled MFMA GEMM ----------------
__global__ __launch_bounds__(256) void kC(const unsigned short* __restrict__ Hn,
                                          const unsigned short* __restrict__ WmT,
                                          const float* __restrict__ bm,
                                          float* __restrict__ out) {
    __shared__ __align__(16) unsigned short As[2][64*64];
    __shared__ __align__(16) unsigned short Bs[2][96*64];
    const int t = threadIdx.x, w = t >> 6, lane = t & 63, m = lane & 15, g = lane >> 4;
    const int bid = (int)blockIdx.x;
    const int swz = (bid & 7) * 64 + (bid >> 3);
    const int i0 = (swz >> 2) * 64;
    const int n0 = (swz & 3) * 96;
    const int wr = w >> 1, wc = w & 1;

    const f32x4 z4 = {0.f, 0.f, 0.f, 0.f};
    f32x4 acc[2][3];
#pragma unroll
    for (int ms = 0; ms < 2; ++ms)
#pragma unroll
        for (int ns = 0; ns < 3; ++ns) acc[ms][ns] = z4;

#define KC_STAGE(buf, k0)                                                              \
    {                                                                                  \
        _Pragma("unroll")                                                              \
        for (int p = 0; p < 2; ++p) {                                                  \
            const int e = t + 256*p, row = e >> 3, c16 = e & 7;                        \
            gl16(Hn + (size_t)(i0+row)*H_DIM + (k0) + ((c16 ^ (row&7)) << 3),          \
                 (char*)As[buf] + e*16);                                               \
        }                                                                              \
        _Pragma("unroll")                                                              \
        for (int p = 0; p < 3; ++p) {                                                  \
            const int e = t + 256*p, row = e >> 3, c16 = e & 7;                        \
            gl16(WmT + (size_t)(n0+row)*H_DIM + (k0) + ((c16 ^ (row&7)) << 3),         \
                 (char*)Bs[buf] + e*16);                                               \
        }                                                                              \
    }

    KC_STAGE(0, 0);
    __syncthreads();

    for (int s = 0; s < 18; ++s) {
        const int cur = s & 1;
        if (s < 17) KC_STAGE(cur ^ 1, (s + 1) * 64);
#pragma unroll
        for (int kh = 0; kh < 2; ++kh) {
            const int kb = kh*64 + g*16;
            bf16x8 af[2];
#pragma unroll
            for (int ms = 0; ms < 2; ++ms) {
                const int row = wr*32 + ms*16 + m;
                af[ms] = *(const bf16x8*)((const char*)As[cur] + row*128 + (kb ^ ((row&7)<<4)));
            }
#pragma unroll
            for (int ns = 0; ns < 3; ++ns) {
                const int row = wc*48 + ns*16 + m;
                const bf16x8 bf_ = *(const bf16x8*)((const char*)Bs[cur] + row*128 + (kb ^ ((row&7)<<4)));
                acc[0][ns] = __builtin_amdgcn_mfma_f32_16x16x32_bf16(af[0], bf_, acc[0][ns], 0, 0, 0);
                acc[1][ns] = __builtin_amdgcn_mfma_f32_16x16x32_bf16(af[1], bf_, acc[1][ns], 0, 0, 0);
            }
        }
        __syncthreads();
    }
#undef KC_STAGE

#pragma unroll
    for (int ms = 0; ms < 2; ++ms)
#pragma unroll
        for (int ns = 0; ns < 3; ++ns) {
            const int col = n0 + wc*48 + ns*16 + m;
            const float bmv = bm[col];
#pragma unroll
            for (int r = 0; r < 4; ++r) {
                float o = acc[ms][ns][r] + bmv;
                o = fmaxf(o, NEG * o);
                out[(size_t)(i0 + wr*32 + ms*16 + g*4 + r) * OUT_DIM + col] = o;
            }
        }
}

extern "C" void kernel_launch(void* const* d_in, const int* in_sizes, int n_in,
                              void* d_out, int out_size, void* d_ws, size_t ws_size,
                              hipStream_t stream) {
    const float* X  = (const float*)d_in[0];
    const float* Wv = (const float*)d_in[1];
    const float* bv = (const float*)d_in[2];
    const float* Wq = (const float*)d_in[3];
    const float* bq = (const float*)d_in[4];
    const float* Wk = (const float*)d_in[5];
    const float* bk = (const float*)d_in[6];
    const float* Wm = (const float*)d_in[7];
    const float* bm = (const float*)d_in[8];
    float* out = (float*)d_out;

    char* p = (char*)d_ws;
    unsigned short* VT  = (unsigned short*)p;                 p += (size_t)BB*F_HID*NN*2;
    float*          Qw  = (float*)p;                          p += (size_t)ROWS*HEADS*4;
    float*          Kw  = (float*)p;                          p += (size_t)ROWS*HEADS*4;
    unsigned short* WmT = (unsigned short*)p;                 p += (size_t)F_OUT*H_DIM*2;
    unsigned short* Hn  = (unsigned short*)p;
    (void)ws_size; (void)out_size; (void)n_in; (void)in_sizes;

    kW<<<(H_DIM/32)*(F_OUT/32), 256, 0, stream>>>(Wm, WmT);
    kA<<<ROWS/8, 256, 0, stream>>>(X, Wv, bv, Wq, bq, Wk, bk, VT, Qw, Kw);
    kB<<<BB*(NN/16), 512, 0, stream>>>(X, VT, Qw, Kw, out, Hn);
    kC<<<ROWS/64 * (F_OUT/96), 256, 0, stream>>>(Hn, WmT, bm, out);
}

// Round 7
// 100.881 us; speedup vs baseline: 1.6796x; 1.6796x over previous
//
#include <hip/hip_runtime.h>
#include <hip/hip_bf16.h>
#include <math.h>

#define BB 8
#define NN 1024
#define F_IN 384
#define F_HID 96
#define HEADS 8
#define F_OUT 384
#define ROWS (BB*NN)                 // 8192
#define H_DIM 1152                   // HEADS*F_HID + F_IN
#define OUT_DIM 1536                 // F_OUT + H_DIM
#define NEG 0.01f
#define LN_EPS 1e-5f

typedef __bf16 bf16x8 __attribute__((ext_vector_type(8)));
typedef float  f32x4  __attribute__((ext_vector_type(4)));

static __device__ __forceinline__ unsigned short b16u(float x) {
    union { __bf16 h; unsigned short u; } c; c.h = (__bf16)x; return c.u;
}

typedef __attribute__((address_space(1))) const unsigned char g1_t;
typedef __attribute__((address_space(3))) unsigned char l3_t;
static __device__ __forceinline__ void gl16(const void* g, void* l) {
    __builtin_amdgcn_global_load_lds((g1_t*)g, (l3_t*)l, 16, 0, 0);
}

// ---------------- kW: WmT[n][k] = bf16(Wm[k][n]) ; WvT[f][k] = bf16(Wv[k][f]) ----
// blocks 0..431: Wm (36 k-tiles x 12 n-tiles); blocks 432..467: Wv (12 k x 3 f)
__global__ __launch_bounds__(256) void kW(const float* __restrict__ Wm,
                                          const float* __restrict__ Wv,
                                          unsigned short* __restrict__ WmT,
                                          unsigned short* __restrict__ WvT) {
    __shared__ float tile[32][33];
    const int t = threadIdx.x;
    const int bid = (int)blockIdx.x;
    const float* src; unsigned short* dst;
    int k0, n0, srcld, dstld;
    if (bid < 432) {
        k0 = (bid / 12) * 32; n0 = (bid % 12) * 32;
        src = Wm; dst = WmT; srcld = F_OUT; dstld = H_DIM;
    } else {
        const int e = bid - 432;
        k0 = (e / 3) * 32; n0 = (e % 3) * 32;
        src = Wv; dst = WvT; srcld = F_HID; dstld = F_IN;
    }
#pragma unroll
    for (int p = 0; p < 4; ++p) {
        const int e = t + 256*p, kk = e >> 5, nn = e & 31;
        tile[kk][nn] = src[(size_t)(k0 + kk) * srcld + n0 + nn];
    }
    __syncthreads();
#pragma unroll
    for (int p = 0; p < 4; ++p) {
        const int e = t + 256*p, nn = e >> 5, kk = e & 31;
        dst[(size_t)(n0 + nn) * dstld + k0 + kk] = b16u(tile[kk][nn]);
    }
}

// ---------------- kA1: Xn = bf16(LN(X)) ----------------
__global__ __launch_bounds__(256) void kA1(const float* __restrict__ X,
                                           unsigned short* __restrict__ Xn) {
    const int t = threadIdx.x, r = t >> 5, lane = t & 31;
    const int row = blockIdx.x * 8 + r;
    const float4* xrow = (const float4*)(X + (size_t)row * F_IN);
    float4 xv[3];
    float s = 0.f, sq = 0.f;
#pragma unroll
    for (int k = 0; k < 3; ++k) {
        xv[k] = xrow[lane + 32*k];
        s  += xv[k].x + xv[k].y + xv[k].z + xv[k].w;
        sq += xv[k].x*xv[k].x + xv[k].y*xv[k].y + xv[k].z*xv[k].z + xv[k].w*xv[k].w;
    }
#pragma unroll
    for (int m = 1; m < 32; m <<= 1) { s += __shfl_xor(s, m); sq += __shfl_xor(sq, m); }
    const float mu  = s * (1.f/F_IN);
    const float var = sq * (1.f/F_IN) - mu*mu;
    const float rstd = rsqrtf(var + LN_EPS);
#pragma unroll
    for (int k = 0; k < 3; ++k) {
        ushort4 h4;
        h4.x = b16u((xv[k].x - mu) * rstd);
        h4.y = b16u((xv[k].y - mu) * rstd);
        h4.z = b16u((xv[k].z - mu) * rstd);
        h4.w = b16u((xv[k].w - mu) * rstd);
        *(ushort4*)&Xn[(size_t)row * F_IN + 4*(lane + 32*k)] = h4;
    }
}

// ---------------- kA2: V = Xn @ Wv + bv (MFMA, frags direct from global) ----------
// 256 thr = 4 waves; block = 32 rows; wave = (ih, fh): 16 rows x 48 f; grid 256
__global__ __launch_bounds__(256) void kA2(const unsigned short* __restrict__ Xn,
                                           const unsigned short* __restrict__ WvT,
                                           const float* __restrict__ bv,
                                           const float* __restrict__ Wq, const float* __restrict__ bq,
                                           const float* __restrict__ Wk, const float* __restrict__ bk,
                                           unsigned short* __restrict__ VT,
                                           float* __restrict__ Qw, float* __restrict__ Kw) {
    __shared__ float vsh[96][33];   // V transposed [f][i], pad 33
    const int t = threadIdx.x, w = t >> 6, lane = t & 63, m = lane & 15, g = lane >> 4;
    const int bid = (int)blockIdx.x;
    const int swz = (bid & 7) * 32 + (bid >> 3);   // bijective XCD swizzle (256%8==0)
    const int i0 = swz * 32;
    const int b = i0 >> 10, i_in = i0 & 1023;
    const int ih = w >> 1, fh = w & 1;

    const f32x4 z4 = {0.f, 0.f, 0.f, 0.f};
    f32x4 acc[3];
#pragma unroll
    for (int fb = 0; fb < 3; ++fb) acc[fb] = z4;

    // A-frag: row (i0 + ih*16 + m), k = ks*32 + g*8 + e  (Xn rows are linear, L2-hot)
    const unsigned short* Ar = Xn + (size_t)(i0 + ih*16 + m) * F_IN + g*8;
    for (int ks = 0; ks < 12; ++ks) {
        const bf16x8 af = *(const bf16x8*)(Ar + ks*32);
#pragma unroll
        for (int fb = 0; fb < 3; ++fb) {
            const int f = fh*48 + fb*16 + m;
            const bf16x8 bfr = *(const bf16x8*)(WvT + (size_t)f*F_IN + ks*32 + g*8);
            acc[fb] = __builtin_amdgcn_mfma_f32_16x16x32_bf16(af, bfr, acc[fb], 0, 0, 0);
        }
    }

    // V (+bias) -> vsh[f][i]   (C/D: col=lane&15 -> f, row=g*4+r -> i)
#pragma unroll
    for (int fb = 0; fb < 3; ++fb) {
        const int f = fh*48 + fb*16 + m;
        const float bvv = bv[f];
#pragma unroll
        for (int r = 0; r < 4; ++r)
            vsh[f][ih*16 + g*4 + r] = acc[fb][r] + bvv;
    }
    __syncthreads();

    // VT[b][f][i] bf16
#pragma unroll
    for (int p = 0; p < 3; ++p) {
        const int u = t + 256*p, f = u >> 3, ic = (u & 7) * 4;
        ushort4 h4;
        h4.x = b16u(vsh[f][ic]);   h4.y = b16u(vsh[f][ic+1]);
        h4.z = b16u(vsh[f][ic+2]); h4.w = b16u(vsh[f][ic+3]);
        *(ushort4*)&VT[((size_t)b * F_HID + f) * NN + i_in + ic] = h4;
    }

    // Q, K: unit = (i_loc, h)
    {
        const int i_loc = t & 31, h = t >> 5;
        float qa = bq[h], ka = bk[h];
#pragma unroll 8
        for (int f = 0; f < F_HID; ++f) {
            const float v = vsh[f][i_loc];
            qa = fmaf(v, Wq[f*HEADS + h], qa);
            ka = fmaf(v, Wk[f*HEADS + h], ka);
        }
        Qw[(size_t)(i0 + i_loc) * HEADS + h] = qa;
        Kw[(size_t)(i0 + i_loc) * HEADS + h] = ka;
    }
}

// ---------------- kB: pipelined MFMA attention + fused LN(H)  [PROVEN @ R3] ----
// block 256 = 4 waves; 16 i-rows; wave w owns heads {2w,2w+1}; grid 512
__global__ __launch_bounds__(256) void kB(const float* __restrict__ X,
                                          const unsigned short* __restrict__ VT,
                                          const float* __restrict__ Qw,
                                          const float* __restrict__ Kw,
                                          float* __restrict__ out,
                                          unsigned short* __restrict__ Hn) {
    __shared__ float q_sh[16][8];
    __shared__ float k_sh[2][32][9];
    __shared__ __align__(16) unsigned short Wt[2][HEADS][16][40];   // 20 KB (pad 80B rows)
    __shared__ __align__(16) unsigned short vt_sh[2][F_HID][40];    // 15 KB
    __shared__ float lnS[4][16], lnQ2[4][16];
    __shared__ float mu_sh[16], rs_sh[16];

    const int t = threadIdx.x;
    const int bid = (int)blockIdx.x;
    const int swz = (bid & 7) * 64 + (bid >> 3);   // bijective XCD swizzle (512%8==0)
    const int b  = swz >> 6;                       // each XCD owns one batch b
    const int i0 = (swz & 63) * 16;
    const int w = t >> 6, l = t & 63, m = l & 15, g = l >> 4;
    const int si = t >> 4, sj = t & 15;

    if (t < 128) ((float*)q_sh)[t] = Qw[((size_t)(b*NN + i0)) * HEADS + t];

    const f32x4 z4 = {0.f, 0.f, 0.f, 0.f};
    f32x4 acc[2][6];
#pragma unroll
    for (int h = 0; h < 2; ++h)
#pragma unroll
        for (int fb = 0; fb < 6; ++fb) acc[h][fb] = z4;

    const size_t vtbase = (size_t)b * F_HID * NN;
    const size_t krow   = (size_t)b * NN;

    // prologue: stage chunk 0
    {
        const float kr = Kw[(krow + (t >> 3)) * HEADS + (t & 7)];
        ushort4 vr[3];
#pragma unroll
        for (int p = 0; p < 3; ++p) {
            const int e = t + 256*p, f = e >> 3, sub = e & 7;
            vr[p] = *(const ushort4*)(VT + vtbase + (size_t)f * NN + sub*4);
        }
        k_sh[0][t >> 3][t & 7] = kr;
#pragma unroll
        for (int p = 0; p < 3; ++p) {
            const int e = t + 256*p, f = e >> 3, sub = e & 7;
            *(ushort4*)&vt_sh[0][f][sub*4] = vr[p];
        }
    }
    __syncthreads();

    float q[8];
#pragma unroll
    for (int h = 0; h < 8; ++h) q[h] = q_sh[si][h];

    // softmax(0) -> Wt[0]
    {
        const float* kr0 = k_sh[0][2*sj];
        float wE[8], wO[8];
        float sE = 0.f, sO = 0.f;
#pragma unroll
        for (int h = 0; h < 8; ++h) {
            float a0v = q[h]*kr0[h];   a0v = fmaxf(a0v, NEG*a0v);
            float a1v = q[h]*kr0[9+h]; a1v = fmaxf(a1v, NEG*a1v);
            wE[h] = __expf(a0v); sE += wE[h];
            wO[h] = __expf(a1v); sO += wO[h];
        }
        const float iE = 1.f/sE, iO = 1.f/sO;
#pragma unroll
        for (int h = 0; h < 8; ++h)
            *(unsigned int*)&Wt[0][h][si][2*sj] =
                (unsigned int)b16u(wE[h]*iE) | ((unsigned int)b16u(wO[h]*iO) << 16);
    }
    __syncthreads();

    for (int ch = 0; ch < 32; ++ch) {
        const int cur = ch & 1, nxt = cur ^ 1;
        const bool more = (ch < 31);

        // phase A: issue next chunk's global loads into registers
        float kr = 0.f; ushort4 vr[3];
        if (more) {
            const int j0n = (ch + 1) * 32;
            kr = Kw[(krow + j0n + (t >> 3)) * HEADS + (t & 7)];
#pragma unroll
            for (int p = 0; p < 3; ++p) {
                const int e = t + 256*p, f = e >> 3, sub = e & 7;
                vr[p] = *(const ushort4*)(VT + vtbase + (size_t)f * NN + j0n + sub*4);
            }
        }

        // phase B: MFMA on current chunk
        const bf16x8 a0 = *(const bf16x8*)&Wt[cur][2*w    ][m][g*8];
        const bf16x8 a1 = *(const bf16x8*)&Wt[cur][2*w + 1][m][g*8];
#pragma unroll
        for (int fb = 0; fb < 6; ++fb) {
            const bf16x8 bv_ = *(const bf16x8*)&vt_sh[cur][fb*16 + m][g*8];
            acc[0][fb] = __builtin_amdgcn_mfma_f32_16x16x32_bf16(a0, bv_, acc[0][fb], 0, 0, 0);
            acc[1][fb] = __builtin_amdgcn_mfma_f32_16x16x32_bf16(a1, bv_, acc[1][fb], 0, 0, 0);
        }

        if (more) {
            // phase C: write staged regs -> LDS[nxt]
            k_sh[nxt][t >> 3][t & 7] = kr;
#pragma unroll
            for (int p = 0; p < 3; ++p) {
                const int e = t + 256*p, f = e >> 3, sub = e & 7;
                *(ushort4*)&vt_sh[nxt][f][sub*4] = vr[p];
            }
            __syncthreads();
            // phase D: softmax(ch+1) -> Wt[nxt]
            {
                const float* kr0 = k_sh[nxt][2*sj];
                float wE[8], wO[8];
                float sE = 0.f, sO = 0.f;
#pragma unroll
                for (int h = 0; h < 8; ++h) {
                    float a0v = q[h]*kr0[h];   a0v = fmaxf(a0v, NEG*a0v);
                    float a1v = q[h]*kr0[9+h]; a1v = fmaxf(a1v, NEG*a1v);
                    wE[h] = __expf(a0v); sE += wE[h];
                    wO[h] = __expf(a1v); sO += wO[h];
                }
                const float iE = 1.f/sE, iO = 1.f/sO;
#pragma unroll
                for (int h = 0; h < 8; ++h)
                    *(unsigned int*)&Wt[nxt][h][si][2*sj] =
                        (unsigned int)b16u(wE[h]*iE) | ((unsigned int)b16u(wO[h]*iO) << 16);
            }
            __syncthreads();
        }
    }

    // ---- fused LN(H) ----
    float s[4] = {0,0,0,0}, s2[4] = {0,0,0,0};
#pragma unroll
    for (int h = 0; h < 2; ++h)
#pragma unroll
        for (int fb = 0; fb < 6; ++fb)
#pragma unroll
            for (int r = 0; r < 4; ++r) {
                const float v = acc[h][fb][r];
                s[r] += v; s2[r] += v*v;
            }
#pragma unroll
    for (int msk = 1; msk < 16; msk <<= 1)
#pragma unroll
        for (int r = 0; r < 4; ++r) {
            s[r]  += __shfl_xor(s[r],  msk);
            s2[r] += __shfl_xor(s2[r], msk);
        }
    if (m == 0) {
#pragma unroll
        for (int r = 0; r < 4; ++r) { lnS[w][g*4+r] = s[r]; lnQ2[w][g*4+r] = s2[r]; }
    }
    __syncthreads();

    const int row16 = t >> 4, xl = t & 15;
    const size_t xrow = (size_t)(b*NN + i0 + row16);
    const float4* x4 = (const float4*)(X + xrow * F_IN);
    float4 xs[6];
    float sx = 0.f, sx2 = 0.f;
#pragma unroll
    for (int kk = 0; kk < 6; ++kk) {
        xs[kk] = x4[xl + 16*kk];
        sx  += xs[kk].x + xs[kk].y + xs[kk].z + xs[kk].w;
        sx2 += xs[kk].x*xs[kk].x + xs[kk].y*xs[kk].y + xs[kk].z*xs[kk].z + xs[kk].w*xs[kk].w;
    }
#pragma unroll
    for (int msk = 1; msk < 16; msk <<= 1) { sx += __shfl_xor(sx, msk); sx2 += __shfl_xor(sx2, msk); }
    if (xl == 0) {
        const float tot  = sx  + lnS[0][row16] + lnS[1][row16] + lnS[2][row16] + lnS[3][row16];
        const float tot2 = sx2 + lnQ2[0][row16] + lnQ2[1][row16] + lnQ2[2][row16] + lnQ2[3][row16];
        const float muh = tot * (1.f/H_DIM);
        const float varh = tot2 * (1.f/H_DIM) - muh*muh;
        mu_sh[row16] = muh; rs_sh[row16] = rsqrtf(varh + LN_EPS);
    }
    __syncthreads();

#pragma unroll
    for (int r = 0; r < 4; ++r) {
        const int row = g*4 + r;
        const size_t orow = (size_t)(b*NN + i0 + row);
        const float muh = mu_sh[row], rs = rs_sh[row];
#pragma unroll
        for (int h = 0; h < 2; ++h)
#pragma unroll
            for (int fb = 0; fb < 6; ++fb) {
                const int col = (2*w + h)*F_HID + fb*16 + m;
                const float v = acc[h][fb][r];
                out[orow * OUT_DIM + F_OUT + col] = v;
                Hn[orow * H_DIM + col] = b16u((v - muh) * rs);
            }
    }
    {
        const float muh = mu_sh[row16], rs = rs_sh[row16];
        float4* oX = (float4*)(out + xrow * OUT_DIM + F_OUT + HEADS*F_HID);
#pragma unroll
        for (int kk = 0; kk < 6; ++kk) {
            oX[xl + 16*kk] = xs[kk];
            ushort4 hh;
            hh.x = b16u((xs[kk].x - muh) * rs);
            hh.y = b16u((xs[kk].y - muh) * rs);
            hh.z = b16u((xs[kk].z - muh) * rs);
            hh.w = b16u((xs[kk].w - muh) * rs);
            *(ushort4*)&Hn[xrow * H_DIM + HEADS*F_HID + 4*(xl + 16*kk)] = hh;
        }
    }
}

// ---------------- kC: O = lrelu(Hn @ WmT^T + bm), tiled MFMA GEMM [PROVEN @ R3] ----
__global__ __launch_bounds__(256) void kC(const unsigned short* __restrict__ Hn,
                                          const unsigned short* __restrict__ WmT,
                                          const float* __restrict__ bm,
                                          float* __restrict__ out) {
    __shared__ __align__(16) unsigned short As[2][64*64];
    __shared__ __align__(16) unsigned short Bs[2][96*64];
    const int t = threadIdx.x, w = t >> 6, lane = t & 63, m = lane & 15, g = lane >> 4;
    const int bid = (int)blockIdx.x;
    const int swz = (bid & 7) * 64 + (bid >> 3);
    const int i0 = (swz >> 2) * 64;
    const int n0 = (swz & 3) * 96;
    const int wr = w >> 1, wc = w & 1;

    const f32x4 z4 = {0.f, 0.f, 0.f, 0.f};
    f32x4 acc[2][3];
#pragma unroll
    for (int ms = 0; ms < 2; ++ms)
#pragma unroll
        for (int ns = 0; ns < 3; ++ns) acc[ms][ns] = z4;

#define KC_STAGE(buf, k0)                                                              \
    {                                                                                  \
        _Pragma("unroll")                                                              \
        for (int p = 0; p < 2; ++p) {                                                  \
            const int e = t + 256*p, row = e >> 3, c16 = e & 7;                        \
            gl16(Hn + (size_t)(i0+row)*H_DIM + (k0) + ((c16 ^ (row&7)) << 3),          \
                 (char*)As[buf] + e*16);                                               \
        }                                                                              \
        _Pragma("unroll")                                                              \
        for (int p = 0; p < 3; ++p) {                                                  \
            const int e = t + 256*p, row = e >> 3, c16 = e & 7;                        \
            gl16(WmT + (size_t)(n0+row)*H_DIM + (k0) + ((c16 ^ (row&7)) << 3),         \
                 (char*)Bs[buf] + e*16);                                               \
        }                                                                              \
    }

    KC_STAGE(0, 0);
    __syncthreads();

    for (int s = 0; s < 18; ++s) {
        const int cur = s & 1;
        if (s < 17) KC_STAGE(cur ^ 1, (s + 1) * 64);
#pragma unroll
        for (int kh = 0; kh < 2; ++kh) {
            const int kb = kh*64 + g*16;
            bf16x8 af[2];
#pragma unroll
            for (int ms = 0; ms < 2; ++ms) {
                const int row = wr*32 + ms*16 + m;
                af[ms] = *(const bf16x8*)((const char*)As[cur] + row*128 + (kb ^ ((row&7)<<4)));
            }
#pragma unroll
            for (int ns = 0; ns < 3; ++ns) {
                const int row = wc*48 + ns*16 + m;
                const bf16x8 bf_ = *(const bf16x8*)((const char*)Bs[cur] + row*128 + (kb ^ ((row&7)<<4)));
                acc[0][ns] = __builtin_amdgcn_mfma_f32_16x16x32_bf16(af[0], bf_, acc[0][ns], 0, 0, 0);
                acc[1][ns] = __builtin_amdgcn_mfma_f32_16x16x32_bf16(af[1], bf_, acc[1][ns], 0, 0, 0);
            }
        }
        __syncthreads();
    }
#undef KC_STAGE

#pragma unroll
    for (int ms = 0; ms < 2; ++ms)
#pragma unroll
        for (int ns = 0; ns < 3; ++ns) {
            const int col = n0 + wc*48 + ns*16 + m;
            const float bmv = bm[col];
#pragma unroll
            for (int r = 0; r < 4; ++r) {
                float o = acc[ms][ns][r] + bmv;
                o = fmaxf(o, NEG * o);
                out[(size_t)(i0 + wr*32 + ms*16 + g*4 + r) * OUT_DIM + col] = o;
            }
        }
}

extern "C" void kernel_launch(void* const* d_in, const int* in_sizes, int n_in,
                              void* d_out, int out_size, void* d_ws, size_t ws_size,
                              hipStream_t stream) {
    const float* X  = (const float*)d_in[0];
    const float* Wv = (const float*)d_in[1];
    const float* bv = (const float*)d_in[2];
    const float* Wq = (const float*)d_in[3];
    const float* bq = (const float*)d_in[4];
    const float* Wk = (const float*)d_in[5];
    const float* bk = (const float*)d_in[6];
    const float* Wm = (const float*)d_in[7];
    const float* bm = (const float*)d_in[8];
    float* out = (float*)d_out;

    char* p = (char*)d_ws;
    unsigned short* VT  = (unsigned short*)p;                 p += (size_t)BB*F_HID*NN*2;
    float*          Qw  = (float*)p;                          p += (size_t)ROWS*HEADS*4;
    float*          Kw  = (float*)p;                          p += (size_t)ROWS*HEADS*4;
    unsigned short* WmT = (unsigned short*)p;                 p += (size_t)F_OUT*H_DIM*2;
    unsigned short* WvT = (unsigned short*)p;                 p += (size_t)F_HID*F_IN*2;
    unsigned short* Hn  = (unsigned short*)p;                 // ROWS*H_DIM*2 = 18 MB
    unsigned short* Xn  = Hn;   // alias: Xn fully consumed by kA2 before kB writes Hn
    (void)ws_size; (void)out_size; (void)n_in; (void)in_sizes;

    kW<<<468, 256, 0, stream>>>(Wm, Wv, WmT, WvT);
    kA1<<<ROWS/8, 256, 0, stream>>>(X, Xn);
    kA2<<<ROWS/32, 256, 0, stream>>>(Xn, WvT, bv, Wq, bq, Wk, bk, VT, Qw, Kw);
    kB<<<BB*(NN/16), 256, 0, stream>>>(X, VT, Qw, Kw, out, Hn);
    kC<<<ROWS/64 * (F_OUT/96), 256, 0, stream>>>(Hn, WmT, bm, out);
}

// Round 9
// 95.823 us; speedup vs baseline: 1.7683x; 1.0528x over previous
//
#include <hip/hip_runtime.h>
#include <hip/hip_bf16.h>
#include <math.h>

#define BB 8
#define NN 1024
#define F_IN 384
#define F_HID 96
#define HEADS 8
#define F_OUT 384
#define ROWS (BB*NN)                 // 8192
#define H_DIM 1152                   // HEADS*F_HID + F_IN
#define OUT_DIM 1536                 // F_OUT + H_DIM
#define NEG 0.01f
#define LN_EPS 1e-5f

typedef __bf16 bf16x8 __attribute__((ext_vector_type(8)));
typedef float  f32x4  __attribute__((ext_vector_type(4)));

static __device__ __forceinline__ unsigned short b16u(float x) {
    union { __bf16 h; unsigned short u; } c; c.h = (__bf16)x; return c.u;
}
static __device__ __forceinline__ unsigned int pk2(float lo, float hi) {
    return (unsigned int)b16u(lo) | ((unsigned int)b16u(hi) << 16);
}

typedef __attribute__((address_space(1))) const unsigned char g1_t;
typedef __attribute__((address_space(3))) unsigned char l3_t;
static __device__ __forceinline__ void gl16(const void* g, void* l) {
    __builtin_amdgcn_global_load_lds((g1_t*)g, (l3_t*)l, 16, 0, 0);
}

// ---------------- kW: WmT[n][k] = bf16(Wm[k][n]) ; WvT[f][k] = bf16(Wv[k][f]) ----
__global__ __launch_bounds__(256) void kW(const float* __restrict__ Wm,
                                          const float* __restrict__ Wv,
                                          unsigned short* __restrict__ WmT,
                                          unsigned short* __restrict__ WvT) {
    __shared__ float tile[32][33];
    const int t = threadIdx.x;
    const int bid = (int)blockIdx.x;
    const float* src; unsigned short* dst;
    int k0, n0, srcld, dstld;
    if (bid < 432) {
        k0 = (bid / 12) * 32; n0 = (bid % 12) * 32;
        src = Wm; dst = WmT; srcld = F_OUT; dstld = H_DIM;
    } else {
        const int e = bid - 432;
        k0 = (e / 3) * 32; n0 = (e % 3) * 32;
        src = Wv; dst = WvT; srcld = F_HID; dstld = F_IN;
    }
#pragma unroll
    for (int p = 0; p < 4; ++p) {
        const int e = t + 256*p, kk = e >> 5, nn = e & 31;
        tile[kk][nn] = src[(size_t)(k0 + kk) * srcld + n0 + nn];
    }
    __syncthreads();
#pragma unroll
    for (int p = 0; p < 4; ++p) {
        const int e = t + 256*p, nn = e >> 5, kk = e & 31;
        dst[(size_t)(n0 + nn) * dstld + k0 + kk] = b16u(tile[kk][nn]);
    }
}

// ---------------- kA1: Xn = bf16(LN(X)) ----------------
__global__ __launch_bounds__(256) void kA1(const float* __restrict__ X,
                                           unsigned short* __restrict__ Xn) {
    const int t = threadIdx.x, r = t >> 5, lane = t & 31;
    const int row = blockIdx.x * 8 + r;
    const float4* xrow = (const float4*)(X + (size_t)row * F_IN);
    float4 xv[3];
    float s = 0.f, sq = 0.f;
#pragma unroll
    for (int k = 0; k < 3; ++k) {
        xv[k] = xrow[lane + 32*k];
        s  += xv[k].x + xv[k].y + xv[k].z + xv[k].w;
        sq += xv[k].x*xv[k].x + xv[k].y*xv[k].y + xv[k].z*xv[k].z + xv[k].w*xv[k].w;
    }
#pragma unroll
    for (int m = 1; m < 32; m <<= 1) { s += __shfl_xor(s, m); sq += __shfl_xor(sq, m); }
    const float mu  = s * (1.f/F_IN);
    const float var = sq * (1.f/F_IN) - mu*mu;
    const float rstd = rsqrtf(var + LN_EPS);
#pragma unroll
    for (int k = 0; k < 3; ++k) {
        ushort4 h4;
        h4.x = b16u((xv[k].x - mu) * rstd);
        h4.y = b16u((xv[k].y - mu) * rstd);
        h4.z = b16u((xv[k].z - mu) * rstd);
        h4.w = b16u((xv[k].w - mu) * rstd);
        *(ushort4*)&Xn[(size_t)row * F_IN + 4*(lane + 32*k)] = h4;
    }
}

// ---------------- kA2: V = Xn @ Wv + bv (MFMA, frags direct from global) ----------
__global__ __launch_bounds__(256) void kA2(const unsigned short* __restrict__ Xn,
                                           const unsigned short* __restrict__ WvT,
                                           const float* __restrict__ bv,
                                           const float* __restrict__ Wq, const float* __restrict__ bq,
                                           const float* __restrict__ Wk, const float* __restrict__ bk,
                                           unsigned short* __restrict__ VT,
                                           float* __restrict__ Qw, float* __restrict__ Kw) {
    __shared__ float vsh[96][33];
    const int t = threadIdx.x, w = t >> 6, lane = t & 63, m = lane & 15, g = lane >> 4;
    const int bid = (int)blockIdx.x;
    const int swz = (bid & 7) * 32 + (bid >> 3);
    const int i0 = swz * 32;
    const int b = i0 >> 10, i_in = i0 & 1023;
    const int ih = w >> 1, fh = w & 1;

    const f32x4 z4 = {0.f, 0.f, 0.f, 0.f};
    f32x4 acc[3];
#pragma unroll
    for (int fb = 0; fb < 3; ++fb) acc[fb] = z4;

    const unsigned short* Ar = Xn + (size_t)(i0 + ih*16 + m) * F_IN + g*8;
    for (int ks = 0; ks < 12; ++ks) {
        const bf16x8 af = *(const bf16x8*)(Ar + ks*32);
#pragma unroll
        for (int fb = 0; fb < 3; ++fb) {
            const int f = fh*48 + fb*16 + m;
            const bf16x8 bfr = *(const bf16x8*)(WvT + (size_t)f*F_IN + ks*32 + g*8);
            acc[fb] = __builtin_amdgcn_mfma_f32_16x16x32_bf16(af, bfr, acc[fb], 0, 0, 0);
        }
    }

#pragma unroll
    for (int fb = 0; fb < 3; ++fb) {
        const int f = fh*48 + fb*16 + m;
        const float bvv = bv[f];
#pragma unroll
        for (int r = 0; r < 4; ++r)
            vsh[f][ih*16 + g*4 + r] = acc[fb][r] + bvv;
    }
    __syncthreads();

#pragma unroll
    for (int p = 0; p < 3; ++p) {
        const int u = t + 256*p, f = u >> 3, ic = (u & 7) * 4;
        ushort4 h4;
        h4.x = b16u(vsh[f][ic]);   h4.y = b16u(vsh[f][ic+1]);
        h4.z = b16u(vsh[f][ic+2]); h4.w = b16u(vsh[f][ic+3]);
        *(ushort4*)&VT[((size_t)b * F_HID + f) * NN + i_in + ic] = h4;
    }

    {
        const int i_loc = t & 31, h = t >> 5;
        float qa = bq[h], ka = bk[h];
#pragma unroll 8
        for (int f = 0; f < F_HID; ++f) {
            const float v = vsh[f][i_loc];
            qa = fmaf(v, Wq[f*HEADS + h], qa);
            ka = fmaf(v, Wk[f*HEADS + h], ka);
        }
        Qw[(size_t)(i0 + i_loc) * HEADS + h] = qa;
        Kw[(size_t)(i0 + i_loc) * HEADS + h] = ka;
    }
}

// ---------------- kB: MFMA attention + fused LN(H), LDS-traffic-optimized ----------
// block 256 = 4 waves; 16 i-rows; chunk = 64 j; wave = (hq = w&1 -> 4 heads, fh = w>>1 -> 48 f)
// V-tile = [96 f][64 j] bf16 = 768 x 16B units -> 3 units/thread (R8 bug: was 6)
__global__ __launch_bounds__(256) void kB(const float* __restrict__ X,
                                          const unsigned short* __restrict__ VT,
                                          const float* __restrict__ Qw,
                                          const float* __restrict__ Kw,
                                          float* __restrict__ out,
                                          unsigned short* __restrict__ Hn) {
    __shared__ float q_sh[16][8];
    __shared__ float kT[2][HEADS][64];                            // 4 KB  [buf][h][j]
    __shared__ __align__(16) unsigned short Wt[2][HEADS][16][64]; // 32 KB XOR-swizzled
    __shared__ __align__(16) unsigned short vt_sh[2][F_HID][64];  // 24 KB XOR-swizzled
    __shared__ float lnS[4][16], lnQ2[4][16];
    __shared__ float mu_sh[16], rs_sh[16];

    const int t = threadIdx.x;
    const int bid = (int)blockIdx.x;
    const int swz = (bid & 7) * 64 + (bid >> 3);   // bijective XCD swizzle (512%8==0)
    const int b  = swz >> 6;
    const int i0 = (swz & 63) * 16;
    const int w = t >> 6, l = t & 63, m = l & 15, g = l >> 4;
    const int hq = w & 1, fh = w >> 1;
    const int si = t >> 4, jq = t & 15;            // softmax: row si, j-quad {4jq..4jq+3}

    if (t < 128) ((float*)q_sh)[t] = Qw[((size_t)(b*NN + i0)) * HEADS + t];

    const f32x4 z4 = {0.f, 0.f, 0.f, 0.f};
    f32x4 acc[4][3];
#pragma unroll
    for (int h2 = 0; h2 < 4; ++h2)
#pragma unroll
        for (int fb = 0; fb < 3; ++fb) acc[h2][fb] = z4;

    const size_t vtbase = (size_t)b * F_HID * NN;
    const size_t krow   = (size_t)b * NN;

    // softmax for chunk in kT[kb] -> Wt[db]: thread (si, jq) does 4 j x 8 heads
#define SMAX(kb, db)                                                                   \
    {                                                                                  \
        float kv[8][4];                                                                \
        _Pragma("unroll")                                                              \
        for (int h = 0; h < 8; ++h)                                                    \
            *(float4*)kv[h] = *(const float4*)&kT[kb][h][4*jq];                        \
        float p[4][8], inv[4];                                                         \
        _Pragma("unroll")                                                              \
        for (int qj = 0; qj < 4; ++qj) {                                               \
            float s = 0.f;                                                             \
            _Pragma("unroll")                                                          \
            for (int h = 0; h < 8; ++h) {                                              \
                float a = q[h] * kv[h][qj];                                            \
                a = fmaxf(a, NEG*a);                                                   \
                p[qj][h] = __expf(a); s += p[qj][h];                                   \
            }                                                                          \
            inv[qj] = 1.f / s;                                                         \
        }                                                                              \
        char* wbase = (char*)Wt + (db)*16384 + si*128                                  \
                    + ((((jq>>1) ^ (si & 7))) << 4) + ((jq & 1) << 3);                 \
        _Pragma("unroll")                                                              \
        for (int h = 0; h < 8; ++h) {                                                  \
            uint2 dw;                                                                  \
            dw.x = pk2(p[0][h]*inv[0], p[1][h]*inv[1]);                                \
            dw.y = pk2(p[2][h]*inv[2], p[3][h]*inv[3]);                                \
            *(uint2*)(wbase + h*2048) = dw;                                            \
        }                                                                              \
    }

    // prologue: stage chunk 0 (vt + kT), then softmax(0)
    {
        uint4 vr[3];
#pragma unroll
        for (int p = 0; p < 3; ++p) {
            const int e = t + 256*p, f = e >> 3, u = e & 7;
            vr[p] = *(const uint4*)(VT + vtbase + (size_t)f*NN + u*8);
        }
        const float kr0 = Kw[(krow + (t & 63)) * HEADS + (t >> 6)];
        const int e2 = t + 256;
        const float kr1 = Kw[(krow + (e2 & 63)) * HEADS + (e2 >> 6)];
#pragma unroll
        for (int p = 0; p < 3; ++p) {
            const int e = t + 256*p, f = e >> 3, u = e & 7;
            *(uint4*)((char*)vt_sh + f*128 + ((u ^ (f & 7)) << 4)) = vr[p];
        }
        kT[0][t >> 6][t & 63] = kr0;
        kT[0][e2 >> 6][e2 & 63] = kr1;
    }
    __syncthreads();

    float q[8];
#pragma unroll
    for (int h = 0; h < 8; ++h) q[h] = q_sh[si][h];

    SMAX(0, 0);
    __syncthreads();

    for (int c = 0; c < 16; ++c) {
        const int cur = c & 1, nxt = cur ^ 1;
        const bool more = (c < 15);

        // phase A: issue next chunk's global loads into registers
        uint4 vr[3]; float kr0 = 0.f, kr1 = 0.f;
        if (more) {
            const int j0n = (c + 1) * 64;
#pragma unroll
            for (int p = 0; p < 3; ++p) {
                const int e = t + 256*p, f = e >> 3, u = e & 7;
                vr[p] = *(const uint4*)(VT + vtbase + (size_t)f*NN + j0n + u*8);
            }
            kr0 = Kw[(krow + j0n + (t & 63)) * HEADS + (t >> 6)];
            const int e2 = t + 256;
            kr1 = Kw[(krow + j0n + (e2 & 63)) * HEADS + (e2 >> 6)];
        }

        // phase B: MFMA on current chunk (A = Wt[cur], B = vt_sh[cur])
#pragma unroll
        for (int kh = 0; kh < 2; ++kh) {
            const int swzu = ((kh*4 + g) ^ (m & 7)) << 4;
            bf16x8 af[4];
#pragma unroll
            for (int h2 = 0; h2 < 4; ++h2)
                af[h2] = *(const bf16x8*)((const char*)Wt + cur*16384
                                          + (hq*4 + h2)*2048 + m*128 + swzu);
            bf16x8 bfr[3];
#pragma unroll
            for (int fb = 0; fb < 3; ++fb)
                bfr[fb] = *(const bf16x8*)((const char*)vt_sh + cur*12288
                                           + (fh*48 + fb*16 + m)*128 + swzu);
#pragma unroll
            for (int h2 = 0; h2 < 4; ++h2)
#pragma unroll
                for (int fb = 0; fb < 3; ++fb)
                    acc[h2][fb] = __builtin_amdgcn_mfma_f32_16x16x32_bf16(
                        af[h2], bfr[fb], acc[h2][fb], 0, 0, 0);
        }

        if (more) {
            // phase C: write staged regs -> LDS[nxt]
#pragma unroll
            for (int p = 0; p < 3; ++p) {
                const int e = t + 256*p, f = e >> 3, u = e & 7;
                *(uint4*)((char*)vt_sh + nxt*12288 + f*128 + ((u ^ (f & 7)) << 4)) = vr[p];
            }
            kT[nxt][t >> 6][t & 63] = kr0;
            const int e2 = t + 256;
            kT[nxt][e2 >> 6][e2 & 63] = kr1;
            __syncthreads();
            // phase D: softmax(c+1) -> Wt[nxt]
            SMAX(nxt, nxt);
            __syncthreads();
        }
    }
#undef SMAX

    // ---- fused LN(H): per-row sums from accs ----
    float s[4] = {0,0,0,0}, s2[4] = {0,0,0,0};
#pragma unroll
    for (int h2 = 0; h2 < 4; ++h2)
#pragma unroll
        for (int fb = 0; fb < 3; ++fb)
#pragma unroll
            for (int r = 0; r < 4; ++r) {
                const float v = acc[h2][fb][r];
                s[r] += v; s2[r] += v*v;
            }
#pragma unroll
    for (int msk = 1; msk < 16; msk <<= 1)
#pragma unroll
        for (int r = 0; r < 4; ++r) {
            s[r]  += __shfl_xor(s[r],  msk);
            s2[r] += __shfl_xor(s2[r], msk);
        }
    if (m == 0) {
#pragma unroll
        for (int r = 0; r < 4; ++r) { lnS[w][g*4+r] = s[r]; lnQ2[w][g*4+r] = s2[r]; }
    }
    __syncthreads();

    const int row16 = t >> 4, xl = t & 15;
    const size_t xrow = (size_t)(b*NN + i0 + row16);
    const float4* x4 = (const float4*)(X + xrow * F_IN);
    float4 xs[6];
    float sx = 0.f, sx2 = 0.f;
#pragma unroll
    for (int kk = 0; kk < 6; ++kk) {
        xs[kk] = x4[xl + 16*kk];
        sx  += xs[kk].x + xs[kk].y + xs[kk].z + xs[kk].w;
        sx2 += xs[kk].x*xs[kk].x + xs[kk].y*xs[kk].y + xs[kk].z*xs[kk].z + xs[kk].w*xs[kk].w;
    }
#pragma unroll
    for (int msk = 1; msk < 16; msk <<= 1) { sx += __shfl_xor(sx, msk); sx2 += __shfl_xor(sx2, msk); }
    if (xl == 0) {
        const float tot  = sx  + lnS[0][row16] + lnS[1][row16] + lnS[2][row16] + lnS[3][row16];
        const float tot2 = sx2 + lnQ2[0][row16] + lnQ2[1][row16] + lnQ2[2][row16] + lnQ2[3][row16];
        const float muh = tot * (1.f/H_DIM);
        const float varh = tot2 * (1.f/H_DIM) - muh*muh;
        mu_sh[row16] = muh; rs_sh[row16] = rsqrtf(varh + LN_EPS);
    }
    __syncthreads();

    // Hh: fp32 to out cols [384..1152), bf16-normalized to Hn cols [0..768)
#pragma unroll
    for (int r = 0; r < 4; ++r) {
        const int row = g*4 + r;
        const size_t orow = (size_t)(b*NN + i0 + row);
        const float muh = mu_sh[row], rs = rs_sh[row];
#pragma unroll
        for (int h2 = 0; h2 < 4; ++h2)
#pragma unroll
            for (int fb = 0; fb < 3; ++fb) {
                const int col = (hq*4 + h2)*F_HID + fh*48 + fb*16 + m;
                const float v = acc[h2][fb][r];
                out[orow * OUT_DIM + F_OUT + col] = v;
                Hn[orow * H_DIM + col] = b16u((v - muh) * rs);
            }
    }
    {
        const float muh = mu_sh[row16], rs = rs_sh[row16];
        float4* oX = (float4*)(out + xrow * OUT_DIM + F_OUT + HEADS*F_HID);
#pragma unroll
        for (int kk = 0; kk < 6; ++kk) {
            oX[xl + 16*kk] = xs[kk];
            ushort4 hh;
            hh.x = b16u((xs[kk].x - muh) * rs);
            hh.y = b16u((xs[kk].y - muh) * rs);
            hh.z = b16u((xs[kk].z - muh) * rs);
            hh.w = b16u((xs[kk].w - muh) * rs);
            *(ushort4*)&Hn[xrow * H_DIM + HEADS*F_HID + 4*(xl + 16*kk)] = hh;
        }
    }
}

// ---------------- kC: O = lrelu(Hn @ WmT^T + bm), tiled MFMA GEMM [PROVEN] ----
__global__ __launch_bounds__(256) void kC(const unsigned short* __restrict__ Hn,
                                          const unsigned short* __restrict__ WmT,
                                          const float* __restrict__ bm,
                                          float* __restrict__ out) {
    __shared__ __align__(16) unsigned short As[2][64*64];
    __shared__ __align__(16) unsigned short Bs[2][96*64];
    const int t = threadIdx.x, w = t >> 6, lane = t & 63, m = lane & 15, g = lane >> 4;
    const int bid = (int)blockIdx.x;
    const int swz = (bid & 7) * 64 + (bid >> 3);
    const int i0 = (swz >> 2) * 64;
    const int n0 = (swz & 3) * 96;
    const int wr = w >> 1, wc = w & 1;

    const f32x4 z4 = {0.f, 0.f, 0.f, 0.f};
    f32x4 acc[2][3];
#pragma unroll
    for (int ms = 0; ms < 2; ++ms)
#pragma unroll
        for (int ns = 0; ns < 3; ++ns) acc[ms][ns] = z4;

#define KC_STAGE(buf, k0)                                                              \
    {                                                                                  \
        _Pragma("unroll")                                                              \
        for (int p = 0; p < 2; ++p) {                                                  \
            const int e = t + 256*p, row = e >> 3, c16 = e & 7;                        \
            gl16(Hn + (size_t)(i0+row)*H_DIM + (k0) + ((c16 ^ (row&7)) << 3),          \
                 (char*)As[buf] + e*16);                                               \
        }                                                                              \
        _Pragma("unroll")                                                              \
        for (int p = 0; p < 3; ++p) {                                                  \
            const int e = t + 256*p, row = e >> 3, c16 = e & 7;                        \
            gl16(WmT + (size_t)(n0+row)*H_DIM + (k0) + ((c16 ^ (row&7)) << 3),         \
                 (char*)Bs[buf] + e*16);                                               \
        }                                                                              \
    }

    KC_STAGE(0, 0);
    __syncthreads();

    for (int s = 0; s < 18; ++s) {
        const int cur = s & 1;
        if (s < 17) KC_STAGE(cur ^ 1, (s + 1) * 64);
#pragma unroll
        for (int kh = 0; kh < 2; ++kh) {
            const int kb = kh*64 + g*16;
            bf16x8 af[2];
#pragma unroll
            for (int ms = 0; ms < 2; ++ms) {
                const int row = wr*32 + ms*16 + m;
                af[ms] = *(const bf16x8*)((const char*)As[cur] + row*128 + (kb ^ ((row&7)<<4)));
            }
#pragma unroll
            for (int ns = 0; ns < 3; ++ns) {
                const int row = wc*48 + ns*16 + m;
                const bf16x8 bf_ = *(const bf16x8*)((const char*)Bs[cur] + row*128 + (kb ^ ((row&7)<<4)));
                acc[0][ns] = __builtin_amdgcn_mfma_f32_16x16x32_bf16(af[0], bf_, acc[0][ns], 0, 0, 0);
                acc[1][ns] = __builtin_amdgcn_mfma_f32_16x16x32_bf16(af[1], bf_, acc[1][ns], 0, 0, 0);
            }
        }
        __syncthreads();
    }
#undef KC_STAGE

#pragma unroll
    for (int ms = 0; ms < 2; ++ms)
#pragma unroll
        for (int ns = 0; ns < 3; ++ns) {
            const int col = n0 + wc*48 + ns*16 + m;
            const float bmv = bm[col];
#pragma unroll
            for (int r = 0; r < 4; ++r) {
                float o = acc[ms][ns][r] + bmv;
                o = fmaxf(o, NEG * o);
                out[(size_t)(i0 + wr*32 + ms*16 + g*4 + r) * OUT_DIM + col] = o;
            }
        }
}

extern "C" void kernel_launch(void* const* d_in, const int* in_sizes, int n_in,
                              void* d_out, int out_size, void* d_ws, size_t ws_size,
                              hipStream_t stream) {
    const float* X  = (const float*)d_in[0];
    const float* Wv = (const float*)d_in[1];
    const float* bv = (const float*)d_in[2];
    const float* Wq = (const float*)d_in[3];
    const float* bq = (const float*)d_in[4];
    const float* Wk = (const float*)d_in[5];
    const float* bk = (const float*)d_in[6];
    const float* Wm = (const float*)d_in[7];
    const float* bm = (const float*)d_in[8];
    float* out = (float*)d_out;

    char* p = (char*)d_ws;
    unsigned short* VT  = (unsigned short*)p;                 p += (size_t)BB*F_HID*NN*2;
    float*          Qw  = (float*)p;                          p += (size_t)ROWS*HEADS*4;
    float*          Kw  = (float*)p;                          p += (size_t)ROWS*HEADS*4;
    unsigned short* WmT = (unsigned short*)p;                 p += (size_t)F_OUT*H_DIM*2;
    unsigned short* WvT = (unsigned short*)p;                 p += (size_t)F_HID*F_IN*2;
    unsigned short* Hn  = (unsigned short*)p;                 // ROWS*H_DIM*2 = 18 MB
    unsigned short* Xn  = Hn;   // alias: Xn fully consumed by kA2 before kB writes Hn
    (void)ws_size; (void)out_size; (void)n_in; (void)in_sizes;

    kW<<<468, 256, 0, stream>>>(Wm, Wv, WmT, WvT);
    kA1<<<ROWS/8, 256, 0, stream>>>(X, Xn);
    kA2<<<ROWS/32, 256, 0, stream>>>(Xn, WvT, bv, Wq, bq, Wk, bk, VT, Qw, Kw);
    kB<<<BB*(NN/16), 256, 0, stream>>>(X, VT, Qw, Kw, out, Hn);
    kC<<<ROWS/64 * (F_OUT/96), 256, 0, stream>>>(Hn, WmT, bm, out);
}

// Round 10
// 92.010 us; speedup vs baseline: 1.8416x; 1.0414x over previous
//
#include <hip/hip_runtime.h>
#include <hip/hip_bf16.h>
#include <math.h>

#define BB 8
#define NN 1024
#define F_IN 384
#define F_HID 96
#define HEADS 8
#define F_OUT 384
#define ROWS (BB*NN)                 // 8192
#define H_DIM 1152                   // HEADS*F_HID + F_IN
#define OUT_DIM 1536                 // F_OUT + H_DIM
#define NEG 0.01f
#define LN_EPS 1e-5f
#define LOG2E 1.4426950408889634f

typedef __bf16 bf16x8 __attribute__((ext_vector_type(8)));
typedef float  f32x4  __attribute__((ext_vector_type(4)));

static __device__ __forceinline__ unsigned short b16u(float x) {
    union { __bf16 h; unsigned short u; } c; c.h = (__bf16)x; return c.u;
}
static __device__ __forceinline__ unsigned int pk2(float lo, float hi) {
    return (unsigned int)b16u(lo) | ((unsigned int)b16u(hi) << 16);
}

typedef __attribute__((address_space(1))) const unsigned char g1_t;
typedef __attribute__((address_space(3))) unsigned char l3_t;
static __device__ __forceinline__ void gl16(const void* g, void* l) {
    __builtin_amdgcn_global_load_lds((g1_t*)g, (l3_t*)l, 16, 0, 0);
}

// ---------------- kW: WmT[n][k] = bf16(Wm[k][n]) ; WvT[f][k] = bf16(Wv[k][f]) ----
__global__ __launch_bounds__(256) void kW(const float* __restrict__ Wm,
                                          const float* __restrict__ Wv,
                                          unsigned short* __restrict__ WmT,
                                          unsigned short* __restrict__ WvT) {
    __shared__ float tile[32][33];
    const int t = threadIdx.x;
    const int bid = (int)blockIdx.x;
    const float* src; unsigned short* dst;
    int k0, n0, srcld, dstld;
    if (bid < 432) {
        k0 = (bid / 12) * 32; n0 = (bid % 12) * 32;
        src = Wm; dst = WmT; srcld = F_OUT; dstld = H_DIM;
    } else {
        const int e = bid - 432;
        k0 = (e / 3) * 32; n0 = (e % 3) * 32;
        src = Wv; dst = WvT; srcld = F_HID; dstld = F_IN;
    }
#pragma unroll
    for (int p = 0; p < 4; ++p) {
        const int e = t + 256*p, kk = e >> 5, nn = e & 31;
        tile[kk][nn] = src[(size_t)(k0 + kk) * srcld + n0 + nn];
    }
    __syncthreads();
#pragma unroll
    for (int p = 0; p < 4; ++p) {
        const int e = t + 256*p, nn = e >> 5, kk = e & 31;
        dst[(size_t)(n0 + nn) * dstld + k0 + kk] = b16u(tile[kk][nn]);
    }
}

// ---------------- kA1: Xn = bf16(LN(X)) ----------------
__global__ __launch_bounds__(256) void kA1(const float* __restrict__ X,
                                           unsigned short* __restrict__ Xn) {
    const int t = threadIdx.x, r = t >> 5, lane = t & 31;
    const int row = blockIdx.x * 8 + r;
    const float4* xrow = (const float4*)(X + (size_t)row * F_IN);
    float4 xv[3];
    float s = 0.f, sq = 0.f;
#pragma unroll
    for (int k = 0; k < 3; ++k) {
        xv[k] = xrow[lane + 32*k];
        s  += xv[k].x + xv[k].y + xv[k].z + xv[k].w;
        sq += xv[k].x*xv[k].x + xv[k].y*xv[k].y + xv[k].z*xv[k].z + xv[k].w*xv[k].w;
    }
#pragma unroll
    for (int m = 1; m < 32; m <<= 1) { s += __shfl_xor(s, m); sq += __shfl_xor(sq, m); }
    const float mu  = s * (1.f/F_IN);
    const float var = sq * (1.f/F_IN) - mu*mu;
    const float rstd = rsqrtf(var + LN_EPS);
#pragma unroll
    for (int k = 0; k < 3; ++k) {
        ushort4 h4;
        h4.x = b16u((xv[k].x - mu) * rstd);
        h4.y = b16u((xv[k].y - mu) * rstd);
        h4.z = b16u((xv[k].z - mu) * rstd);
        h4.w = b16u((xv[k].w - mu) * rstd);
        *(ushort4*)&Xn[(size_t)row * F_IN + 4*(lane + 32*k)] = h4;
    }
}

// ---------------- kA2: V = Xn @ Wv + bv (MFMA, frags direct from global) ----------
__global__ __launch_bounds__(256) void kA2(const unsigned short* __restrict__ Xn,
                                           const unsigned short* __restrict__ WvT,
                                           const float* __restrict__ bv,
                                           const float* __restrict__ Wq, const float* __restrict__ bq,
                                           const float* __restrict__ Wk, const float* __restrict__ bk,
                                           unsigned short* __restrict__ VT,
                                           float* __restrict__ Qw, float* __restrict__ Kw) {
    __shared__ float vsh[96][33];
    const int t = threadIdx.x, w = t >> 6, lane = t & 63, m = lane & 15, g = lane >> 4;
    const int bid = (int)blockIdx.x;
    const int swz = (bid & 7) * 32 + (bid >> 3);
    const int i0 = swz * 32;
    const int b = i0 >> 10, i_in = i0 & 1023;
    const int ih = w >> 1, fh = w & 1;

    const f32x4 z4 = {0.f, 0.f, 0.f, 0.f};
    f32x4 acc[3];
#pragma unroll
    for (int fb = 0; fb < 3; ++fb) acc[fb] = z4;

    const unsigned short* Ar = Xn + (size_t)(i0 + ih*16 + m) * F_IN + g*8;
    for (int ks = 0; ks < 12; ++ks) {
        const bf16x8 af = *(const bf16x8*)(Ar + ks*32);
#pragma unroll
        for (int fb = 0; fb < 3; ++fb) {
            const int f = fh*48 + fb*16 + m;
            const bf16x8 bfr = *(const bf16x8*)(WvT + (size_t)f*F_IN + ks*32 + g*8);
            acc[fb] = __builtin_amdgcn_mfma_f32_16x16x32_bf16(af, bfr, acc[fb], 0, 0, 0);
        }
    }

#pragma unroll
    for (int fb = 0; fb < 3; ++fb) {
        const int f = fh*48 + fb*16 + m;
        const float bvv = bv[f];
#pragma unroll
        for (int r = 0; r < 4; ++r)
            vsh[f][ih*16 + g*4 + r] = acc[fb][r] + bvv;
    }
    __syncthreads();

#pragma unroll
    for (int p = 0; p < 3; ++p) {
        const int u = t + 256*p, f = u >> 3, ic = (u & 7) * 4;
        ushort4 h4;
        h4.x = b16u(vsh[f][ic]);   h4.y = b16u(vsh[f][ic+1]);
        h4.z = b16u(vsh[f][ic+2]); h4.w = b16u(vsh[f][ic+3]);
        *(ushort4*)&VT[((size_t)b * F_HID + f) * NN + i_in + ic] = h4;
    }

    {
        const int i_loc = t & 31, h = t >> 5;
        float qa = bq[h], ka = bk[h];
#pragma unroll 8
        for (int f = 0; f < F_HID; ++f) {
            const float v = vsh[f][i_loc];
            qa = fmaf(v, Wq[f*HEADS + h], qa);
            ka = fmaf(v, Wk[f*HEADS + h], ka);
        }
        Qw[(size_t)(i0 + i_loc) * HEADS + h] = qa;
        Kw[(size_t)(i0 + i_loc) * HEADS + h] = ka;
    }
}

// ---------------- kB: MFMA attention + fused LN(H), ONE barrier per chunk ----------
// block 256 = 4 waves; 16 i-rows; chunk = 64 j; wave = (hq = w&1 -> 4 heads, fh = w>>1 -> 48 f)
// Iter c: A issue V(c+1)/K(c+2) reg-loads -> B SMAX(c+1)->Wt[nxt] (reads kT[nxt]) ->
//         C MFMA(c) <- Wt[cur],vt[cur] -> D write vt[nxt],kT[cur] -> ONE barrier.
// Buffer audit: B w:Wt[nxt] / C r:Wt[cur]; D w:vt[nxt] / C r:vt[cur]; D w:kT[cur] / B r:kT[nxt].
__global__ __launch_bounds__(256) void kB(const float* __restrict__ X,
                                          const unsigned short* __restrict__ VT,
                                          const float* __restrict__ Qw,
                                          const float* __restrict__ Kw,
                                          float* __restrict__ out,
                                          unsigned short* __restrict__ Hn) {
    __shared__ float q_sh[16][8];
    __shared__ float kT[2][HEADS][64];                            // 4 KB  [buf][h][j]
    __shared__ __align__(16) unsigned short Wt[2][HEADS][16][64]; // 32 KB XOR-swizzled
    __shared__ __align__(16) unsigned short vt_sh[2][F_HID][64];  // 24 KB XOR-swizzled
    __shared__ float lnS[4][16], lnQ2[4][16];
    __shared__ float mu_sh[16], rs_sh[16];

    const int t = threadIdx.x;
    const int bid = (int)blockIdx.x;
    const int swz = (bid & 7) * 64 + (bid >> 3);   // bijective XCD swizzle (512%8==0)
    const int b  = swz >> 6;
    const int i0 = (swz & 63) * 16;
    const int w = t >> 6, l = t & 63, m = l & 15, g = l >> 4;
    const int hq = w & 1, fh = w >> 1;
    const int si = t >> 4, jq = t & 15;            // softmax: row si, j-quad {4jq..4jq+3}

    if (t < 128) ((float*)q_sh)[t] = Qw[((size_t)(b*NN + i0)) * HEADS + t];

    const f32x4 z4 = {0.f, 0.f, 0.f, 0.f};
    f32x4 acc[4][3];
#pragma unroll
    for (int h2 = 0; h2 < 4; ++h2)
#pragma unroll
        for (int fb = 0; fb < 3; ++fb) acc[h2][fb] = z4;

    const size_t vtbase = (size_t)b * F_HID * NN;
    const size_t krow   = (size_t)b * NN;

    // softmax for chunk in kT[kb] -> Wt[db]: thread (si, jq) does 4 j x 8 heads
    // q prescaled by LOG2E; lrelu is positively homogeneous so exp2(lrelu(q'*k)) is exact
#define SMAX(kb, db)                                                                   \
    {                                                                                  \
        float kv[8][4];                                                                \
        _Pragma("unroll")                                                              \
        for (int h = 0; h < 8; ++h)                                                    \
            *(float4*)kv[h] = *(const float4*)&kT[kb][h][4*jq];                        \
        float p[4][8], inv[4];                                                         \
        _Pragma("unroll")                                                              \
        for (int qj = 0; qj < 4; ++qj) {                                               \
            float s = 0.f;                                                             \
            _Pragma("unroll")                                                          \
            for (int h = 0; h < 8; ++h) {                                              \
                float a = q[h] * kv[h][qj];                                            \
                a = fmaxf(a, NEG*a);                                                   \
                p[qj][h] = __builtin_amdgcn_exp2f(a); s += p[qj][h];                   \
            }                                                                          \
            inv[qj] = 1.f / s;                                                         \
        }                                                                              \
        char* wbase = (char*)Wt + (db)*16384 + si*128                                  \
                    + ((((jq>>1) ^ (si & 7))) << 4) + ((jq & 1) << 3);                 \
        _Pragma("unroll")                                                              \
        for (int h = 0; h < 8; ++h) {                                                  \
            uint2 dw;                                                                  \
            dw.x = pk2(p[0][h]*inv[0], p[1][h]*inv[1]);                                \
            dw.y = pk2(p[2][h]*inv[2], p[3][h]*inv[3]);                                \
            *(uint2*)(wbase + h*2048) = dw;                                            \
        }                                                                              \
    }

    // prologue: stage chunk 0 V, K(0), K(1); then softmax(0)
    {
        uint4 vr[3];
#pragma unroll
        for (int p = 0; p < 3; ++p) {
            const int e = t + 256*p, f = e >> 3, u = e & 7;
            vr[p] = *(const uint4*)(VT + vtbase + (size_t)f*NN + u*8);
        }
        const int e2 = t + 256;
        const float ka0 = Kw[(krow + (t & 63)) * HEADS + (t >> 6)];
        const float ka1 = Kw[(krow + (e2 & 63)) * HEADS + (e2 >> 6)];
        const float kb0 = Kw[(krow + 64 + (t & 63)) * HEADS + (t >> 6)];
        const float kb1 = Kw[(krow + 64 + (e2 & 63)) * HEADS + (e2 >> 6)];
#pragma unroll
        for (int p = 0; p < 3; ++p) {
            const int e = t + 256*p, f = e >> 3, u = e & 7;
            *(uint4*)((char*)vt_sh + f*128 + ((u ^ (f & 7)) << 4)) = vr[p];
        }
        kT[0][t >> 6][t & 63] = ka0;
        kT[0][e2 >> 6][e2 & 63] = ka1;
        kT[1][t >> 6][t & 63] = kb0;
        kT[1][e2 >> 6][e2 & 63] = kb1;
    }
    __syncthreads();

    float q[8];
#pragma unroll
    for (int h = 0; h < 8; ++h) q[h] = q_sh[si][h] * LOG2E;

    SMAX(0, 0);
    __syncthreads();

    for (int c = 0; c < 16; ++c) {
        const int cur = c & 1, nxt = cur ^ 1;

        // phase A: issue next-chunk reg loads (land under phase B's VALU)
        uint4 vr[3]; float kr0 = 0.f, kr1 = 0.f;
        if (c < 15) {
            const int j0n = (c + 1) * 64;
#pragma unroll
            for (int p = 0; p < 3; ++p) {
                const int e = t + 256*p, f = e >> 3, u = e & 7;
                vr[p] = *(const uint4*)(VT + vtbase + (size_t)f*NN + j0n + u*8);
            }
        }
        if (c < 14) {
            const int j0k = (c + 2) * 64;
            kr0 = Kw[(krow + j0k + (t & 63)) * HEADS + (t >> 6)];
            const int e2 = t + 256;
            kr1 = Kw[(krow + j0k + (e2 & 63)) * HEADS + (e2 >> 6)];
        }

        // phase B: softmax(c+1) -> Wt[nxt] (reads kT[nxt], staged 2 ahead)
        if (c < 15) SMAX(nxt, nxt);

        // phase C: MFMA chunk c (A = Wt[cur], B = vt_sh[cur])
#pragma unroll
        for (int kh = 0; kh < 2; ++kh) {
            const int swzu = ((kh*4 + g) ^ (m & 7)) << 4;
            bf16x8 af[4];
#pragma unroll
            for (int h2 = 0; h2 < 4; ++h2)
                af[h2] = *(const bf16x8*)((const char*)Wt + cur*16384
                                          + (hq*4 + h2)*2048 + m*128 + swzu);
            bf16x8 bfr[3];
#pragma unroll
            for (int fb = 0; fb < 3; ++fb)
                bfr[fb] = *(const bf16x8*)((const char*)vt_sh + cur*12288
                                           + (fh*48 + fb*16 + m)*128 + swzu);
#pragma unroll
            for (int h2 = 0; h2 < 4; ++h2)
#pragma unroll
                for (int fb = 0; fb < 3; ++fb)
                    acc[h2][fb] = __builtin_amdgcn_mfma_f32_16x16x32_bf16(
                        af[h2], bfr[fb], acc[h2][fb], 0, 0, 0);
        }

        // phase D: write staged regs -> vt_sh[nxt], kT[cur] (chunk c+2)
        if (c < 15) {
#pragma unroll
            for (int p = 0; p < 3; ++p) {
                const int e = t + 256*p, f = e >> 3, u = e & 7;
                *(uint4*)((char*)vt_sh + nxt*12288 + f*128 + ((u ^ (f & 7)) << 4)) = vr[p];
            }
        }
        if (c < 14) {
            kT[cur][t >> 6][t & 63] = kr0;
            const int e2 = t + 256;
            kT[cur][e2 >> 6][e2 & 63] = kr1;
        }
        __syncthreads();   // single barrier: publishes Wt[nxt], vt[nxt], kT[cur]
    }
#undef SMAX

    // ---- fused LN(H): per-row sums from accs ----
    float s[4] = {0,0,0,0}, s2[4] = {0,0,0,0};
#pragma unroll
    for (int h2 = 0; h2 < 4; ++h2)
#pragma unroll
        for (int fb = 0; fb < 3; ++fb)
#pragma unroll
            for (int r = 0; r < 4; ++r) {
                const float v = acc[h2][fb][r];
                s[r] += v; s2[r] += v*v;
            }
#pragma unroll
    for (int msk = 1; msk < 16; msk <<= 1)
#pragma unroll
        for (int r = 0; r < 4; ++r) {
            s[r]  += __shfl_xor(s[r],  msk);
            s2[r] += __shfl_xor(s2[r], msk);
        }
    if (m == 0) {
#pragma unroll
        for (int r = 0; r < 4; ++r) { lnS[w][g*4+r] = s[r]; lnQ2[w][g*4+r] = s2[r]; }
    }
    __syncthreads();

    const int row16 = t >> 4, xl = t & 15;
    const size_t xrow = (size_t)(b*NN + i0 + row16);
    const float4* x4 = (const float4*)(X + xrow * F_IN);
    float4 xs[6];
    float sx = 0.f, sx2 = 0.f;
#pragma unroll
    for (int kk = 0; kk < 6; ++kk) {
        xs[kk] = x4[xl + 16*kk];
        sx  += xs[kk].x + xs[kk].y + xs[kk].z + xs[kk].w;
        sx2 += xs[kk].x*xs[kk].x + xs[kk].y*xs[kk].y + xs[kk].z*xs[kk].z + xs[kk].w*xs[kk].w;
    }
#pragma unroll
    for (int msk = 1; msk < 16; msk <<= 1) { sx += __shfl_xor(sx, msk); sx2 += __shfl_xor(sx2, msk); }
    if (xl == 0) {
        const float tot  = sx  + lnS[0][row16] + lnS[1][row16] + lnS[2][row16] + lnS[3][row16];
        const float tot2 = sx2 + lnQ2[0][row16] + lnQ2[1][row16] + lnQ2[2][row16] + lnQ2[3][row16];
        const float muh = tot * (1.f/H_DIM);
        const float varh = tot2 * (1.f/H_DIM) - muh*muh;
        mu_sh[row16] = muh; rs_sh[row16] = rsqrtf(varh + LN_EPS);
    }
    __syncthreads();

    // Hh: fp32 to out cols [384..1152), bf16-normalized to Hn cols [0..768)
#pragma unroll
    for (int r = 0; r < 4; ++r) {
        const int row = g*4 + r;
        const size_t orow = (size_t)(b*NN + i0 + row);
        const float muh = mu_sh[row], rs = rs_sh[row];
#pragma unroll
        for (int h2 = 0; h2 < 4; ++h2)
#pragma unroll
            for (int fb = 0; fb < 3; ++fb) {
                const int col = (hq*4 + h2)*F_HID + fh*48 + fb*16 + m;
                const float v = acc[h2][fb][r];
                out[orow * OUT_DIM + F_OUT + col] = v;
                Hn[orow * H_DIM + col] = b16u((v - muh) * rs);
            }
    }
    {
        const float muh = mu_sh[row16], rs = rs_sh[row16];
        float4* oX = (float4*)(out + xrow * OUT_DIM + F_OUT + HEADS*F_HID);
#pragma unroll
        for (int kk = 0; kk < 6; ++kk) {
            oX[xl + 16*kk] = xs[kk];
            ushort4 hh;
            hh.x = b16u((xs[kk].x - muh) * rs);
            hh.y = b16u((xs[kk].y - muh) * rs);
            hh.z = b16u((xs[kk].z - muh) * rs);
            hh.w = b16u((xs[kk].w - muh) * rs);
            *(ushort4*)&Hn[xrow * H_DIM + HEADS*F_HID + 4*(xl + 16*kk)] = hh;
        }
    }
}

// ---------------- kC: O = lrelu(Hn @ WmT^T + bm), tiled MFMA GEMM [PROVEN] ----
__global__ __launch_bounds__(256) void kC(const unsigned short* __restrict__ Hn,
                                          const unsigned short* __restrict__ WmT,
                                          const float* __restrict__ bm,
                                          float* __restrict__ out) {
    __shared__ __align__(16) unsigned short As[2][64*64];
    __shared__ __align__(16) unsigned short Bs[2][96*64];
    const int t = threadIdx.x, w = t >> 6, lane = t & 63, m = lane & 15, g = lane >> 4;
    const int bid = (int)blockIdx.x;
    const int swz = (bid & 7) * 64 + (bid >> 3);
    const int i0 = (swz >> 2) * 64;
    const int n0 = (swz & 3) * 96;
    const int wr = w >> 1, wc = w & 1;

    const f32x4 z4 = {0.f, 0.f, 0.f, 0.f};
    f32x4 acc[2][3];
#pragma unroll
    for (int ms = 0; ms < 2; ++ms)
#pragma unroll
        for (int ns = 0; ns < 3; ++ns) acc[ms][ns] = z4;

#define KC_STAGE(buf, k0)                                                              \
    {                                                                                  \
        _Pragma("unroll")                                                              \
        for (int p = 0; p < 2; ++p) {                                                  \
            const int e = t + 256*p, row = e >> 3, c16 = e & 7;                        \
            gl16(Hn + (size_t)(i0+row)*H_DIM + (k0) + ((c16 ^ (row&7)) << 3),          \
                 (char*)As[buf] + e*16);                                               \
        }                                                                              \
        _Pragma("unroll")                                                              \
        for (int p = 0; p < 3; ++p) {                                                  \
            const int e = t + 256*p, row = e >> 3, c16 = e & 7;                        \
            gl16(WmT + (size_t)(n0+row)*H_DIM + (k0) + ((c16 ^ (row&7)) << 3),         \
                 (char*)Bs[buf] + e*16);                                               \
        }                                                                              \
    }

    KC_STAGE(0, 0);
    __syncthreads();

    for (int s = 0; s < 18; ++s) {
        const int cur = s & 1;
        if (s < 17) KC_STAGE(cur ^ 1, (s + 1) * 64);
#pragma unroll
        for (int kh = 0; kh < 2; ++kh) {
            const int kb = kh*64 + g*16;
            bf16x8 af[2];
#pragma unroll
            for (int ms = 0; ms < 2; ++ms) {
                const int row = wr*32 + ms*16 + m;
                af[ms] = *(const bf16x8*)((const char*)As[cur] + row*128 + (kb ^ ((row&7)<<4)));
            }
#pragma unroll
            for (int ns = 0; ns < 3; ++ns) {
                const int row = wc*48 + ns*16 + m;
                const bf16x8 bf_ = *(const bf16x8*)((const char*)Bs[cur] + row*128 + (kb ^ ((row&7)<<4)));
                acc[0][ns] = __builtin_amdgcn_mfma_f32_16x16x32_bf16(af[0], bf_, acc[0][ns], 0, 0, 0);
                acc[1][ns] = __builtin_amdgcn_mfma_f32_16x16x32_bf16(af[1], bf_, acc[1][ns], 0, 0, 0);
            }
        }
        __syncthreads();
    }
#undef KC_STAGE

#pragma unroll
    for (int ms = 0; ms < 2; ++ms)
#pragma unroll
        for (int ns = 0; ns < 3; ++ns) {
            const int col = n0 + wc*48 + ns*16 + m;
            const float bmv = bm[col];
#pragma unroll
            for (int r = 0; r < 4; ++r) {
                float o = acc[ms][ns][r] + bmv;
                o = fmaxf(o, NEG * o);
                out[(size_t)(i0 + wr*32 + ms*16 + g*4 + r) * OUT_DIM + col] = o;
            }
        }
}

extern "C" void kernel_launch(void* const* d_in, const int* in_sizes, int n_in,
                              void* d_out, int out_size, void* d_ws, size_t ws_size,
                              hipStream_t stream) {
    const float* X  = (const float*)d_in[0];
    const float* Wv = (const float*)d_in[1];
    const float* bv = (const float*)d_in[2];
    const float* Wq = (const float*)d_in[3];
    const float* bq = (const float*)d_in[4];
    const float* Wk = (const float*)d_in[5];
    const float* bk = (const float*)d_in[6];
    const float* Wm = (const float*)d_in[7];
    const float* bm = (const float*)d_in[8];
    float* out = (float*)d_out;

    char* p = (char*)d_ws;
    unsigned short* VT  = (unsigned short*)p;                 p += (size_t)BB*F_HID*NN*2;
    float*          Qw  = (float*)p;                          p += (size_t)ROWS*HEADS*4;
    float*          Kw  = (float*)p;                          p += (size_t)ROWS*HEADS*4;
    unsigned short* WmT = (unsigned short*)p;                 p += (size_t)F_OUT*H_DIM*2;
    unsigned short* WvT = (unsigned short*)p;                 p += (size_t)F_HID*F_IN*2;
    unsigned short* Hn  = (unsigned short*)p;                 // ROWS*H_DIM*2 = 18 MB
    unsigned short* Xn  = Hn;   // alias: Xn fully consumed by kA2 before kB writes Hn
    (void)ws_size; (void)out_size; (void)n_in; (void)in_sizes;

    kW<<<468, 256, 0, stream>>>(Wm, Wv, WmT, WvT);
    kA1<<<ROWS/8, 256, 0, stream>>>(X, Xn);
    kA2<<<ROWS/32, 256, 0, stream>>>(Xn, WvT, bv, Wq, bq, Wk, bk, VT, Qw, Kw);
    kB<<<BB*(NN/16), 256, 0, stream>>>(X, VT, Qw, Kw, out, Hn);
    kC<<<ROWS/64 * (F_OUT/96), 256, 0, stream>>>(Hn, WmT, bm, out);
}

// Round 11
// 90.003 us; speedup vs baseline: 1.8826x; 1.0223x over previous
//
#include <hip/hip_runtime.h>
#include <hip/hip_bf16.h>
#include <math.h>

#define BB 8
#define NN 1024
#define F_IN 384
#define F_HID 96
#define HEADS 8
#define F_OUT 384
#define ROWS (BB*NN)                 // 8192
#define H_DIM 1152                   // HEADS*F_HID + F_IN
#define OUT_DIM 1536                 // F_OUT + H_DIM
#define NEG 0.01f
#define LN_EPS 1e-5f
#define LOG2E 1.4426950408889634f

typedef __bf16 bf16x8 __attribute__((ext_vector_type(8)));
typedef float  f32x4  __attribute__((ext_vector_type(4)));

static __device__ __forceinline__ unsigned short b16u(float x) {
    union { __bf16 h; unsigned short u; } c; c.h = (__bf16)x; return c.u;
}
static __device__ __forceinline__ unsigned int pk2(float lo, float hi) {
    return (unsigned int)b16u(lo) | ((unsigned int)b16u(hi) << 16);
}

typedef __attribute__((address_space(1))) const unsigned char g1_t;
typedef __attribute__((address_space(3))) unsigned char l3_t;
static __device__ __forceinline__ void gl16(const void* g, void* l) {
    __builtin_amdgcn_global_load_lds((g1_t*)g, (l3_t*)l, 16, 0, 0);
}

// ---------------- kW: WmT[n][k] = bf16(Wm[k][n]) ; WvT[f][k] = bf16(Wv[k][f]) ----
__global__ __launch_bounds__(256) void kW(const float* __restrict__ Wm,
                                          const float* __restrict__ Wv,
                                          unsigned short* __restrict__ WmT,
                                          unsigned short* __restrict__ WvT) {
    __shared__ float tile[32][33];
    const int t = threadIdx.x;
    const int bid = (int)blockIdx.x;
    const float* src; unsigned short* dst;
    int k0, n0, srcld, dstld;
    if (bid < 432) {
        k0 = (bid / 12) * 32; n0 = (bid % 12) * 32;
        src = Wm; dst = WmT; srcld = F_OUT; dstld = H_DIM;
    } else {
        const int e = bid - 432;
        k0 = (e / 3) * 32; n0 = (e % 3) * 32;
        src = Wv; dst = WvT; srcld = F_HID; dstld = F_IN;
    }
#pragma unroll
    for (int p = 0; p < 4; ++p) {
        const int e = t + 256*p, kk = e >> 5, nn = e & 31;
        tile[kk][nn] = src[(size_t)(k0 + kk) * srcld + n0 + nn];
    }
    __syncthreads();
#pragma unroll
    for (int p = 0; p < 4; ++p) {
        const int e = t + 256*p, nn = e >> 5, kk = e & 31;
        dst[(size_t)(n0 + nn) * dstld + k0 + kk] = b16u(tile[kk][nn]);
    }
}

// ---------------- kA1: Xn = bf16(LN(X)) ----------------
__global__ __launch_bounds__(256) void kA1(const float* __restrict__ X,
                                           unsigned short* __restrict__ Xn) {
    const int t = threadIdx.x, r = t >> 5, lane = t & 31;
    const int row = blockIdx.x * 8 + r;
    const float4* xrow = (const float4*)(X + (size_t)row * F_IN);
    float4 xv[3];
    float s = 0.f, sq = 0.f;
#pragma unroll
    for (int k = 0; k < 3; ++k) {
        xv[k] = xrow[lane + 32*k];
        s  += xv[k].x + xv[k].y + xv[k].z + xv[k].w;
        sq += xv[k].x*xv[k].x + xv[k].y*xv[k].y + xv[k].z*xv[k].z + xv[k].w*xv[k].w;
    }
#pragma unroll
    for (int m = 1; m < 32; m <<= 1) { s += __shfl_xor(s, m); sq += __shfl_xor(sq, m); }
    const float mu  = s * (1.f/F_IN);
    const float var = sq * (1.f/F_IN) - mu*mu;
    const float rstd = rsqrtf(var + LN_EPS);
#pragma unroll
    for (int k = 0; k < 3; ++k) {
        ushort4 h4;
        h4.x = b16u((xv[k].x - mu) * rstd);
        h4.y = b16u((xv[k].y - mu) * rstd);
        h4.z = b16u((xv[k].z - mu) * rstd);
        h4.w = b16u((xv[k].w - mu) * rstd);
        *(ushort4*)&Xn[(size_t)row * F_IN + 4*(lane + 32*k)] = h4;
    }
}

// ---------------- kA2: V = Xn @ Wv + bv (MFMA, frags direct from global) ----------
__global__ __launch_bounds__(256) void kA2(const unsigned short* __restrict__ Xn,
                                           const unsigned short* __restrict__ WvT,
                                           const float* __restrict__ bv,
                                           const float* __restrict__ Wq, const float* __restrict__ bq,
                                           const float* __restrict__ Wk, const float* __restrict__ bk,
                                           unsigned short* __restrict__ VT,
                                           float* __restrict__ Qw, float* __restrict__ Kw) {
    __shared__ float vsh[96][33];
    const int t = threadIdx.x, w = t >> 6, lane = t & 63, m = lane & 15, g = lane >> 4;
    const int bid = (int)blockIdx.x;
    const int swz = (bid & 7) * 32 + (bid >> 3);
    const int i0 = swz * 32;
    const int b = i0 >> 10, i_in = i0 & 1023;
    const int ih = w >> 1, fh = w & 1;

    const f32x4 z4 = {0.f, 0.f, 0.f, 0.f};
    f32x4 acc[3];
#pragma unroll
    for (int fb = 0; fb < 3; ++fb) acc[fb] = z4;

    const unsigned short* Ar = Xn + (size_t)(i0 + ih*16 + m) * F_IN + g*8;
    for (int ks = 0; ks < 12; ++ks) {
        const bf16x8 af = *(const bf16x8*)(Ar + ks*32);
#pragma unroll
        for (int fb = 0; fb < 3; ++fb) {
            const int f = fh*48 + fb*16 + m;
            const bf16x8 bfr = *(const bf16x8*)(WvT + (size_t)f*F_IN + ks*32 + g*8);
            acc[fb] = __builtin_amdgcn_mfma_f32_16x16x32_bf16(af, bfr, acc[fb], 0, 0, 0);
        }
    }

#pragma unroll
    for (int fb = 0; fb < 3; ++fb) {
        const int f = fh*48 + fb*16 + m;
        const float bvv = bv[f];
#pragma unroll
        for (int r = 0; r < 4; ++r)
            vsh[f][ih*16 + g*4 + r] = acc[fb][r] + bvv;
    }
    __syncthreads();

#pragma unroll
    for (int p = 0; p < 3; ++p) {
        const int u = t + 256*p, f = u >> 3, ic = (u & 7) * 4;
        ushort4 h4;
        h4.x = b16u(vsh[f][ic]);   h4.y = b16u(vsh[f][ic+1]);
        h4.z = b16u(vsh[f][ic+2]); h4.w = b16u(vsh[f][ic+3]);
        *(ushort4*)&VT[((size_t)b * F_HID + f) * NN + i_in + ic] = h4;
    }

    {
        const int i_loc = t & 31, h = t >> 5;
        float qa = bq[h], ka = bk[h];
#pragma unroll 8
        for (int f = 0; f < F_HID; ++f) {
            const float v = vsh[f][i_loc];
            qa = fmaf(v, Wq[f*HEADS + h], qa);
            ka = fmaf(v, Wk[f*HEADS + h], ka);
        }
        Qw[(size_t)(i0 + i_loc) * HEADS + h] = qa;
        Kw[(size_t)(i0 + i_loc) * HEADS + h] = ka;
    }
}

// ---------------- kB: MFMA attention + fused LN(H), 8 waves, one barrier/chunk ----
// 512 thr = 8 waves; wave = (hp = w>>1 -> heads {2hp,2hp+1}, fh = w&1 -> 48 f)
// 16 i-rows; chunk = 64 j; R10 single-barrier schedule, reg-staged V/K, dbuf Wt/vt/kT.
// SMAX: thread (si = t>>5, jd = t&31) handles j in {2jd, 2jd+1} x 8 heads.
__global__ __launch_bounds__(512, 4) void kB(const float* __restrict__ X,
                                             const unsigned short* __restrict__ VT,
                                             const float* __restrict__ Qw,
                                             const float* __restrict__ Kw,
                                             float* __restrict__ out,
                                             unsigned short* __restrict__ Hn) {
    __shared__ float q_sh[16][8];
    __shared__ float kT[2][HEADS][64];                            // 4 KB  [buf][h][j]
    __shared__ __align__(16) unsigned short Wt[2][HEADS][16][64]; // 32 KB XOR-swizzled
    __shared__ __align__(16) unsigned short vt_sh[2][F_HID][64];  // 24 KB XOR-swizzled
    __shared__ float lnS[8][16], lnQ2[8][16];
    __shared__ float sxS[16], sx2S[16];
    __shared__ float mu_sh[16], rs_sh[16];

    const int t = threadIdx.x;
    const int bid = (int)blockIdx.x;
    const int swz = (bid & 7) * 64 + (bid >> 3);   // bijective XCD swizzle (512%8==0)
    const int b  = swz >> 6;
    const int i0 = (swz & 63) * 16;
    const int w = t >> 6, l = t & 63, m = l & 15, g = l >> 4;
    const int hp = w >> 1, fh = w & 1;
    const int si = t >> 5, jd = t & 31;

    if (t < 128) ((float*)q_sh)[t] = Qw[((size_t)(b*NN + i0)) * HEADS + t];

    const f32x4 z4 = {0.f, 0.f, 0.f, 0.f};
    f32x4 acc[2][3];
#pragma unroll
    for (int h2 = 0; h2 < 2; ++h2)
#pragma unroll
        for (int fb = 0; fb < 3; ++fb) acc[h2][fb] = z4;

    const size_t vtbase = (size_t)b * F_HID * NN;
    const size_t krow   = (size_t)b * NN;

    // softmax: kT[kb] -> Wt[db]; thread (si, jd): j = 2jd, 2jd+1, all 8 heads
#define SMAX(kb, db)                                                                   \
    {                                                                                  \
        float2 kk[8];                                                                  \
        _Pragma("unroll")                                                              \
        for (int h = 0; h < 8; ++h)                                                    \
            kk[h] = *(const float2*)&kT[kb][h][2*jd];                                  \
        float p0[8], p1[8];                                                            \
        float s0 = 0.f, s1 = 0.f;                                                      \
        _Pragma("unroll")                                                              \
        for (int h = 0; h < 8; ++h) {                                                  \
            float a0 = q[h] * kk[h].x; a0 = fmaxf(a0, NEG*a0);                         \
            float a1 = q[h] * kk[h].y; a1 = fmaxf(a1, NEG*a1);                         \
            p0[h] = __builtin_amdgcn_exp2f(a0); s0 += p0[h];                           \
            p1[h] = __builtin_amdgcn_exp2f(a1); s1 += p1[h];                           \
        }                                                                              \
        const float inv0 = 1.f / s0, inv1 = 1.f / s1;                                  \
        char* wbase = (char*)Wt + (db)*16384 + si*128                                  \
                    + ((((jd>>2) ^ (si & 7))) << 4) + ((jd & 3) << 2);                 \
        _Pragma("unroll")                                                              \
        for (int h = 0; h < 8; ++h)                                                    \
            *(unsigned int*)(wbase + h*2048) = pk2(p0[h]*inv0, p1[h]*inv1);            \
    }

    // prologue: stage V(0), kT[0]=K(0), kT[1]=K(1)
    {
        uint4 vr0, vr1;
        {
            const int f = t >> 3, u = t & 7;
            vr0 = *(const uint4*)(VT + vtbase + (size_t)f*NN + u*8);
        }
        if (t < 256) {
            const int e = t + 512, f2 = e >> 3, u2 = e & 7;
            vr1 = *(const uint4*)(VT + vtbase + (size_t)f2*NN + u2*8);
        }
        const float ka = Kw[(krow + l) * HEADS + w];
        const float kb_ = Kw[(krow + 64 + l) * HEADS + w];
        {
            const int f = t >> 3, u = t & 7;
            *(uint4*)((char*)vt_sh + f*128 + ((u ^ (f & 7)) << 4)) = vr0;
        }
        if (t < 256) {
            const int e = t + 512, f2 = e >> 3, u2 = e & 7;
            *(uint4*)((char*)vt_sh + f2*128 + ((u2 ^ (f2 & 7)) << 4)) = vr1;
        }
        kT[0][w][l] = ka;
        kT[1][w][l] = kb_;
    }
    __syncthreads();

    float q[8];
#pragma unroll
    for (int h = 0; h < 8; ++h) q[h] = q_sh[si][h] * LOG2E;

    SMAX(0, 0);
    __syncthreads();

    for (int c = 0; c < 16; ++c) {
        const int cur = c & 1, nxt = cur ^ 1;

        // phase A: issue next-chunk reg loads
        uint4 vr0, vr1; float kr = 0.f;
        if (c < 15) {
            const int j0n = (c + 1) * 64;
            {
                const int f = t >> 3, u = t & 7;
                vr0 = *(const uint4*)(VT + vtbase + (size_t)f*NN + j0n + u*8);
            }
            if (t < 256) {
                const int e = t + 512, f2 = e >> 3, u2 = e & 7;
                vr1 = *(const uint4*)(VT + vtbase + (size_t)f2*NN + j0n + u2*8);
            }
        }
        if (c < 14) kr = Kw[(krow + (size_t)(c + 2)*64 + l) * HEADS + w];

        // phase B: softmax(c+1) -> Wt[nxt] (reads kT[nxt])
        if (c < 15) SMAX(nxt, nxt);

        // phase C: MFMA chunk c (A = Wt[cur] heads {2hp,2hp+1}, B = vt_sh[cur] fh-half)
#pragma unroll
        for (int kh = 0; kh < 2; ++kh) {
            const int swzu = ((kh*4 + g) ^ (m & 7)) << 4;
            bf16x8 af[2];
#pragma unroll
            for (int h2 = 0; h2 < 2; ++h2)
                af[h2] = *(const bf16x8*)((const char*)Wt + cur*16384
                                          + (hp*2 + h2)*2048 + m*128 + swzu);
            bf16x8 bfr[3];
#pragma unroll
            for (int fb = 0; fb < 3; ++fb)
                bfr[fb] = *(const bf16x8*)((const char*)vt_sh + cur*12288
                                           + (fh*48 + fb*16 + m)*128 + swzu);
#pragma unroll
            for (int h2 = 0; h2 < 2; ++h2)
#pragma unroll
                for (int fb = 0; fb < 3; ++fb)
                    acc[h2][fb] = __builtin_amdgcn_mfma_f32_16x16x32_bf16(
                        af[h2], bfr[fb], acc[h2][fb], 0, 0, 0);
        }

        // phase D: write staged regs -> vt_sh[nxt], kT[cur] (chunk c+2)
        if (c < 15) {
            {
                const int f = t >> 3, u = t & 7;
                *(uint4*)((char*)vt_sh + nxt*12288 + f*128 + ((u ^ (f & 7)) << 4)) = vr0;
            }
            if (t < 256) {
                const int e = t + 512, f2 = e >> 3, u2 = e & 7;
                *(uint4*)((char*)vt_sh + nxt*12288 + f2*128 + ((u2 ^ (f2 & 7)) << 4)) = vr1;
            }
        }
        if (c < 14) kT[cur][w][l] = kr;
        __syncthreads();   // single barrier: publishes Wt[nxt], vt[nxt], kT[cur]
    }
#undef SMAX

    // ---- fused LN(H): per-row sums from accs (8-wave reduction) ----
    float s[4] = {0,0,0,0}, s2[4] = {0,0,0,0};
#pragma unroll
    for (int h2 = 0; h2 < 2; ++h2)
#pragma unroll
        for (int fb = 0; fb < 3; ++fb)
#pragma unroll
            for (int r = 0; r < 4; ++r) {
                const float v = acc[h2][fb][r];
                s[r] += v; s2[r] += v*v;
            }
#pragma unroll
    for (int msk = 1; msk < 16; msk <<= 1)
#pragma unroll
        for (int r = 0; r < 4; ++r) {
            s[r]  += __shfl_xor(s[r],  msk);
            s2[r] += __shfl_xor(s2[r], msk);
        }
    if (m == 0) {
#pragma unroll
        for (int r = 0; r < 4; ++r) { lnS[w][g*4+r] = s[r]; lnQ2[w][g*4+r] = s2[r]; }
    }

    // X phase: 16 rows x 32 lanes, 3 float4 each
    const int rX = t >> 5, lX = t & 31;
    const size_t xrow = (size_t)(b*NN + i0 + rX);
    const float4* x4 = (const float4*)(X + xrow * F_IN);
    float4 xs[3];
    float sx = 0.f, sx2 = 0.f;
#pragma unroll
    for (int kk = 0; kk < 3; ++kk) {
        xs[kk] = x4[lX + 32*kk];
        sx  += xs[kk].x + xs[kk].y + xs[kk].z + xs[kk].w;
        sx2 += xs[kk].x*xs[kk].x + xs[kk].y*xs[kk].y + xs[kk].z*xs[kk].z + xs[kk].w*xs[kk].w;
    }
#pragma unroll
    for (int msk = 1; msk < 32; msk <<= 1) { sx += __shfl_xor(sx, msk); sx2 += __shfl_xor(sx2, msk); }
    if (lX == 0) { sxS[rX] = sx; sx2S[rX] = sx2; }
    __syncthreads();

    if (t < 16) {
        float tot = sxS[t], tot2 = sx2S[t];
#pragma unroll
        for (int ww = 0; ww < 8; ++ww) { tot += lnS[ww][t]; tot2 += lnQ2[ww][t]; }
        const float muh = tot * (1.f/H_DIM);
        const float varh = tot2 * (1.f/H_DIM) - muh*muh;
        mu_sh[t] = muh; rs_sh[t] = rsqrtf(varh + LN_EPS);
    }
    __syncthreads();

    // Hh: fp32 to out cols [384..1152), bf16-normalized to Hn cols [0..768)
#pragma unroll
    for (int r = 0; r < 4; ++r) {
        const int row = g*4 + r;
        const size_t orow = (size_t)(b*NN + i0 + row);
        const float muh = mu_sh[row], rs = rs_sh[row];
#pragma unroll
        for (int h2 = 0; h2 < 2; ++h2)
#pragma unroll
            for (int fb = 0; fb < 3; ++fb) {
                const int col = (hp*2 + h2)*F_HID + fh*48 + fb*16 + m;
                const float v = acc[h2][fb][r];
                out[orow * OUT_DIM + F_OUT + col] = v;
                Hn[orow * H_DIM + col] = b16u((v - muh) * rs);
            }
    }
    // X passthrough + normalized
    {
        const float muh = mu_sh[rX], rs = rs_sh[rX];
        float4* oX = (float4*)(out + xrow * OUT_DIM + F_OUT + HEADS*F_HID);
#pragma unroll
        for (int kk = 0; kk < 3; ++kk) {
            oX[lX + 32*kk] = xs[kk];
            ushort4 hh;
            hh.x = b16u((xs[kk].x - muh) * rs);
            hh.y = b16u((xs[kk].y - muh) * rs);
            hh.z = b16u((xs[kk].z - muh) * rs);
            hh.w = b16u((xs[kk].w - muh) * rs);
            *(ushort4*)&Hn[xrow * H_DIM + HEADS*F_HID + 4*(lX + 32*kk)] = hh;
        }
    }
}

// ---------------- kC: O = lrelu(Hn @ WmT^T + bm), tiled MFMA GEMM [PROVEN] ----
__global__ __launch_bounds__(256) void kC(const unsigned short* __restrict__ Hn,
                                          const unsigned short* __restrict__ WmT,
                                          const float* __restrict__ bm,
                                          float* __restrict__ out) {
    __shared__ __align__(16) unsigned short As[2][64*64];
    __shared__ __align__(16) unsigned short Bs[2][96*64];
    const int t = threadIdx.x, w = t >> 6, lane = t & 63, m = lane & 15, g = lane >> 4;
    const int bid = (int)blockIdx.x;
    const int swz = (bid & 7) * 64 + (bid >> 3);
    const int i0 = (swz >> 2) * 64;
    const int n0 = (swz & 3) * 96;
    const int wr = w >> 1, wc = w & 1;

    const f32x4 z4 = {0.f, 0.f, 0.f, 0.f};
    f32x4 acc[2][3];
#pragma unroll
    for (int ms = 0; ms < 2; ++ms)
#pragma unroll
        for (int ns = 0; ns < 3; ++ns) acc[ms][ns] = z4;

#define KC_STAGE(buf, k0)                                                              \
    {                                                                                  \
        _Pragma("unroll")                                                              \
        for (int p = 0; p < 2; ++p) {                                                  \
            const int e = t + 256*p, row = e >> 3, c16 = e & 7;                        \
            gl16(Hn + (size_t)(i0+row)*H_DIM + (k0) + ((c16 ^ (row&7)) << 3),          \
                 (char*)As[buf] + e*16);                                               \
        }                                                                              \
        _Pragma("unroll")                                                              \
        for (int p = 0; p < 3; ++p) {                                                  \
            const int e = t + 256*p, row = e >> 3, c16 = e & 7;                        \
            gl16(WmT + (size_t)(n0+row)*H_DIM + (k0) + ((c16 ^ (row&7)) << 3),         \
                 (char*)Bs[buf] + e*16);                                               \
        }                                                                              \
    }

    KC_STAGE(0, 0);
    __syncthreads();

    for (int s = 0; s < 18; ++s) {
        const int cur = s & 1;
        if (s < 17) KC_STAGE(cur ^ 1, (s + 1) * 64);
#pragma unroll
        for (int kh = 0; kh < 2; ++kh) {
            const int kb = kh*64 + g*16;
            bf16x8 af[2];
#pragma unroll
            for (int ms = 0; ms < 2; ++ms) {
                const int row = wr*32 + ms*16 + m;
                af[ms] = *(const bf16x8*)((const char*)As[cur] + row*128 + (kb ^ ((row&7)<<4)));
            }
#pragma unroll
            for (int ns = 0; ns < 3; ++ns) {
                const int row = wc*48 + ns*16 + m;
                const bf16x8 bf_ = *(const bf16x8*)((const char*)Bs[cur] + row*128 + (kb ^ ((row&7)<<4)));
                acc[0][ns] = __builtin_amdgcn_mfma_f32_16x16x32_bf16(af[0], bf_, acc[0][ns], 0, 0, 0);
                acc[1][ns] = __builtin_amdgcn_mfma_f32_16x16x32_bf16(af[1], bf_, acc[1][ns], 0, 0, 0);
            }
        }
        __syncthreads();
    }
#undef KC_STAGE

#pragma unroll
    for (int ms = 0; ms < 2; ++ms)
#pragma unroll
        for (int ns = 0; ns < 3; ++ns) {
            const int col = n0 + wc*48 + ns*16 + m;
            const float bmv = bm[col];
#pragma unroll
            for (int r = 0; r < 4; ++r) {
                float o = acc[ms][ns][r] + bmv;
                o = fmaxf(o, NEG * o);
                out[(size_t)(i0 + wr*32 + ms*16 + g*4 + r) * OUT_DIM + col] = o;
            }
        }
}

extern "C" void kernel_launch(void* const* d_in, const int* in_sizes, int n_in,
                              void* d_out, int out_size, void* d_ws, size_t ws_size,
                              hipStream_t stream) {
    const float* X  = (const float*)d_in[0];
    const float* Wv = (const float*)d_in[1];
    const float* bv = (const float*)d_in[2];
    const float* Wq = (const float*)d_in[3];
    const float* bq = (const float*)d_in[4];
    const float* Wk = (const float*)d_in[5];
    const float* bk = (const float*)d_in[6];
    const float* Wm = (const float*)d_in[7];
    const float* bm = (const float*)d_in[8];
    float* out = (float*)d_out;

    char* p = (char*)d_ws;
    unsigned short* VT  = (unsigned short*)p;                 p += (size_t)BB*F_HID*NN*2;
    float*          Qw  = (float*)p;                          p += (size_t)ROWS*HEADS*4;
    float*          Kw  = (float*)p;                          p += (size_t)ROWS*HEADS*4;
    unsigned short* WmT = (unsigned short*)p;                 p += (size_t)F_OUT*H_DIM*2;
    unsigned short* WvT = (unsigned short*)p;                 p += (size_t)F_HID*F_IN*2;
    unsigned short* Hn  = (unsigned short*)p;                 // ROWS*H_DIM*2 = 18 MB
    unsigned short* Xn  = Hn;   // alias: Xn fully consumed by kA2 before kB writes Hn
    (void)ws_size; (void)out_size; (void)n_in; (void)in_sizes;

    kW<<<468, 256, 0, stream>>>(Wm, Wv, WmT, WvT);
    kA1<<<ROWS/8, 256, 0, stream>>>(X, Xn);
    kA2<<<ROWS/32, 256, 0, stream>>>(Xn, WvT, bv, Wq, bq, Wk, bk, VT, Qw, Kw);
    kB<<<BB*(NN/16), 512, 0, stream>>>(X, VT, Qw, Kw, out, Hn);
    kC<<<ROWS/64 * (F_OUT/96), 256, 0, stream>>>(Hn, WmT, bm, out);
}

// Round 12
// 72.391 us; speedup vs baseline: 2.3406x; 1.2433x over previous
//
#include <hip/hip_runtime.h>
#include <hip/hip_bf16.h>
#include <math.h>

#define BB 8
#define NN 1024
#define F_IN 384
#define F_HID 96
#define HEADS 8
#define F_OUT 384
#define ROWS (BB*NN)                 // 8192
#define H_DIM 1152                   // HEADS*F_HID + F_IN
#define OUT_DIM 1536                 // F_OUT + H_DIM
#define NEG 0.01f
#define LN_EPS 1e-5f
#define LOG2E 1.4426950408889634f

typedef __bf16 bf16x8 __attribute__((ext_vector_type(8)));
typedef float  f32x4  __attribute__((ext_vector_type(4)));

static __device__ __forceinline__ unsigned short b16u(float x) {
    union { __bf16 h; unsigned short u; } c; c.h = (__bf16)x; return c.u;
}
static __device__ __forceinline__ unsigned int pk2(float lo, float hi) {
    return (unsigned int)b16u(lo) | ((unsigned int)b16u(hi) << 16);
}

typedef __attribute__((address_space(1))) const unsigned char g1_t;
typedef __attribute__((address_space(3))) unsigned char l3_t;
static __device__ __forceinline__ void gl16(const void* g, void* l) {
    __builtin_amdgcn_global_load_lds((g1_t*)g, (l3_t*)l, 16, 0, 0);
}

// ---------------- kW: WmT[n][k] = bf16(Wm[k][n]) ; WvT[f][k] = bf16(Wv[k][f]) ----
__global__ __launch_bounds__(256) void kW(const float* __restrict__ Wm,
                                          const float* __restrict__ Wv,
                                          unsigned short* __restrict__ WmT,
                                          unsigned short* __restrict__ WvT) {
    __shared__ float tile[32][33];
    const int t = threadIdx.x;
    const int bid = (int)blockIdx.x;
    const float* src; unsigned short* dst;
    int k0, n0, srcld, dstld;
    if (bid < 432) {
        k0 = (bid / 12) * 32; n0 = (bid % 12) * 32;
        src = Wm; dst = WmT; srcld = F_OUT; dstld = H_DIM;
    } else {
        const int e = bid - 432;
        k0 = (e / 3) * 32; n0 = (e % 3) * 32;
        src = Wv; dst = WvT; srcld = F_HID; dstld = F_IN;
    }
#pragma unroll
    for (int p = 0; p < 4; ++p) {
        const int e = t + 256*p, kk = e >> 5, nn = e & 31;
        tile[kk][nn] = src[(size_t)(k0 + kk) * srcld + n0 + nn];
    }
    __syncthreads();
#pragma unroll
    for (int p = 0; p < 4; ++p) {
        const int e = t + 256*p, nn = e >> 5, kk = e & 31;
        dst[(size_t)(n0 + nn) * dstld + k0 + kk] = b16u(tile[kk][nn]);
    }
}

// ---------------- kA: fused LN(X) -> bf16 (LDS) -> V = MFMA(Xn, WvT) -> VT, Q, K ----
// 384 thr = 6 waves; 16 rows/block; grid 512; wave w owns f-tile [w*16, w*16+16)
__global__ __launch_bounds__(384) void kA(const float* __restrict__ X,
                                          const unsigned short* __restrict__ WvT,
                                          const float* __restrict__ bv,
                                          const float* __restrict__ Wq, const float* __restrict__ bq,
                                          const float* __restrict__ Wk, const float* __restrict__ bk,
                                          unsigned short* __restrict__ VT,
                                          float* __restrict__ Qw, float* __restrict__ Kw) {
    __shared__ __align__(16) unsigned short xn[16][392];  // 12.25 KB (784B rows: 2-way-free)
    __shared__ float vsh[96][17];                         // 6.4 KB
    const int t = threadIdx.x;
    const int bid = (int)blockIdx.x;
    const int swz = (bid & 7) * 64 + (bid >> 3);          // bijective XCD swizzle
    const int i0 = swz * 16;
    const int b = i0 >> 10, i_in = i0 & 1023;
    const int w = t >> 6, l = t & 63, m = l & 15, g = l >> 4;

    // ---- LN phase: threads 0..255, 16 threads/row, 6 float4 each ----
    if (t < 256) {
        const int r = t >> 4, l16 = t & 15;
        const float4* xrow = (const float4*)(X + (size_t)(i0 + r) * F_IN);
        float4 xv[6];
        float s = 0.f, sq = 0.f;
#pragma unroll
        for (int k = 0; k < 6; ++k) {
            xv[k] = xrow[l16 + 16*k];
            s  += xv[k].x + xv[k].y + xv[k].z + xv[k].w;
            sq += xv[k].x*xv[k].x + xv[k].y*xv[k].y + xv[k].z*xv[k].z + xv[k].w*xv[k].w;
        }
#pragma unroll
        for (int msk = 1; msk < 16; msk <<= 1) { s += __shfl_xor(s, msk); sq += __shfl_xor(sq, msk); }
        const float mu  = s * (1.f/F_IN);
        const float var = sq * (1.f/F_IN) - mu*mu;
        const float rstd = rsqrtf(var + LN_EPS);
#pragma unroll
        for (int k = 0; k < 6; ++k) {
            ushort4 h4;
            h4.x = b16u((xv[k].x - mu) * rstd);
            h4.y = b16u((xv[k].y - mu) * rstd);
            h4.z = b16u((xv[k].z - mu) * rstd);
            h4.w = b16u((xv[k].w - mu) * rstd);
            *(ushort4*)&xn[r][4*(l16 + 16*k)] = h4;
        }
    }
    __syncthreads();

    // ---- MFMA: wave w computes 16i x 16f tile, K = 384 (12 steps) ----
    const f32x4 z4 = {0.f, 0.f, 0.f, 0.f};
    f32x4 acc = z4;
    const unsigned short* Br = WvT + (size_t)(w*16 + m) * F_IN + g*8;
#pragma unroll
    for (int ks = 0; ks < 12; ++ks) {
        const bf16x8 af  = *(const bf16x8*)&xn[m][ks*32 + g*8];
        const bf16x8 bfr = *(const bf16x8*)(Br + ks*32);
        acc = __builtin_amdgcn_mfma_f32_16x16x32_bf16(af, bfr, acc, 0, 0, 0);
    }
    {
        const int f = w*16 + m;
        const float bvv = bv[f];
#pragma unroll
        for (int r = 0; r < 4; ++r)
            vsh[f][g*4 + r] = acc[r] + bvv;
    }
    __syncthreads();

    // ---- VT[b][f][i] bf16: 96 f x 4 ushort4 = 384 units, 1/thread ----
    {
        const int f = t >> 2, ic = (t & 3) * 4;
        ushort4 h4;
        h4.x = b16u(vsh[f][ic]);   h4.y = b16u(vsh[f][ic+1]);
        h4.z = b16u(vsh[f][ic+2]); h4.w = b16u(vsh[f][ic+3]);
        *(ushort4*)&VT[((size_t)b * F_HID + f) * NN + i_in + ic] = h4;
    }

    // ---- Q, K: 16 rows x 8 heads, Q on t<128, K on 128<=t<256 ----
    if (t < 256) {
        const int i_loc = t & 15, h = (t >> 4) & 7;
        const bool isQ = (t < 128);
        const float* Wx = isQ ? Wq : Wk;
        float a = isQ ? bq[h] : bk[h];
#pragma unroll 8
        for (int f = 0; f < F_HID; ++f)
            a = fmaf(vsh[f][i_loc], Wx[f*HEADS + h], a);
        if (isQ) Qw[(size_t)(i0 + i_loc) * HEADS + h] = a;
        else     Kw[(size_t)(i0 + i_loc) * HEADS + h] = a;
    }
}

// ---------------- kB: MFMA attention + fused LN(H), 8 waves, one barrier/chunk ----
// [PROVEN @ R11, byte-identical]
__global__ __launch_bounds__(512, 4) void kB(const float* __restrict__ X,
                                             const unsigned short* __restrict__ VT,
                                             const float* __restrict__ Qw,
                                             const float* __restrict__ Kw,
                                             float* __restrict__ out,
                                             unsigned short* __restrict__ Hn) {
    __shared__ float q_sh[16][8];
    __shared__ float kT[2][HEADS][64];
    __shared__ __align__(16) unsigned short Wt[2][HEADS][16][64];
    __shared__ __align__(16) unsigned short vt_sh[2][F_HID][64];
    __shared__ float lnS[8][16], lnQ2[8][16];
    __shared__ float sxS[16], sx2S[16];
    __shared__ float mu_sh[16], rs_sh[16];

    const int t = threadIdx.x;
    const int bid = (int)blockIdx.x;
    const int swz = (bid & 7) * 64 + (bid >> 3);
    const int b  = swz >> 6;
    const int i0 = (swz & 63) * 16;
    const int w = t >> 6, l = t & 63, m = l & 15, g = l >> 4;
    const int hp = w >> 1, fh = w & 1;
    const int si = t >> 5, jd = t & 31;

    if (t < 128) ((float*)q_sh)[t] = Qw[((size_t)(b*NN + i0)) * HEADS + t];

    const f32x4 z4 = {0.f, 0.f, 0.f, 0.f};
    f32x4 acc[2][3];
#pragma unroll
    for (int h2 = 0; h2 < 2; ++h2)
#pragma unroll
        for (int fb = 0; fb < 3; ++fb) acc[h2][fb] = z4;

    const size_t vtbase = (size_t)b * F_HID * NN;
    const size_t krow   = (size_t)b * NN;

#define SMAX(kb, db)                                                                   \
    {                                                                                  \
        float2 kk[8];                                                                  \
        _Pragma("unroll")                                                              \
        for (int h = 0; h < 8; ++h)                                                    \
            kk[h] = *(const float2*)&kT[kb][h][2*jd];                                  \
        float p0[8], p1[8];                                                            \
        float s0 = 0.f, s1 = 0.f;                                                      \
        _Pragma("unroll")                                                              \
        for (int h = 0; h < 8; ++h) {                                                  \
            float a0 = q[h] * kk[h].x; a0 = fmaxf(a0, NEG*a0);                         \
            float a1 = q[h] * kk[h].y; a1 = fmaxf(a1, NEG*a1);                         \
            p0[h] = __builtin_amdgcn_exp2f(a0); s0 += p0[h];                           \
            p1[h] = __builtin_amdgcn_exp2f(a1); s1 += p1[h];                           \
        }                                                                              \
        const float inv0 = 1.f / s0, inv1 = 1.f / s1;                                  \
        char* wbase = (char*)Wt + (db)*16384 + si*128                                  \
                    + ((((jd>>2) ^ (si & 7))) << 4) + ((jd & 3) << 2);                 \
        _Pragma("unroll")                                                              \
        for (int h = 0; h < 8; ++h)                                                    \
            *(unsigned int*)(wbase + h*2048) = pk2(p0[h]*inv0, p1[h]*inv1);            \
    }

    {
        uint4 vr0, vr1;
        {
            const int f = t >> 3, u = t & 7;
            vr0 = *(const uint4*)(VT + vtbase + (size_t)f*NN + u*8);
        }
        if (t < 256) {
            const int e = t + 512, f2 = e >> 3, u2 = e & 7;
            vr1 = *(const uint4*)(VT + vtbase + (size_t)f2*NN + u2*8);
        }
        const float ka = Kw[(krow + l) * HEADS + w];
        const float kb_ = Kw[(krow + 64 + l) * HEADS + w];
        {
            const int f = t >> 3, u = t & 7;
            *(uint4*)((char*)vt_sh + f*128 + ((u ^ (f & 7)) << 4)) = vr0;
        }
        if (t < 256) {
            const int e = t + 512, f2 = e >> 3, u2 = e & 7;
            *(uint4*)((char*)vt_sh + f2*128 + ((u2 ^ (f2 & 7)) << 4)) = vr1;
        }
        kT[0][w][l] = ka;
        kT[1][w][l] = kb_;
    }
    __syncthreads();

    float q[8];
#pragma unroll
    for (int h = 0; h < 8; ++h) q[h] = q_sh[si][h] * LOG2E;

    SMAX(0, 0);
    __syncthreads();

    for (int c = 0; c < 16; ++c) {
        const int cur = c & 1, nxt = cur ^ 1;

        uint4 vr0, vr1; float kr = 0.f;
        if (c < 15) {
            const int j0n = (c + 1) * 64;
            {
                const int f = t >> 3, u = t & 7;
                vr0 = *(const uint4*)(VT + vtbase + (size_t)f*NN + j0n + u*8);
            }
            if (t < 256) {
                const int e = t + 512, f2 = e >> 3, u2 = e & 7;
                vr1 = *(const uint4*)(VT + vtbase + (size_t)f2*NN + j0n + u2*8);
            }
        }
        if (c < 14) kr = Kw[(krow + (size_t)(c + 2)*64 + l) * HEADS + w];

        if (c < 15) SMAX(nxt, nxt);

#pragma unroll
        for (int kh = 0; kh < 2; ++kh) {
            const int swzu = ((kh*4 + g) ^ (m & 7)) << 4;
            bf16x8 af[2];
#pragma unroll
            for (int h2 = 0; h2 < 2; ++h2)
                af[h2] = *(const bf16x8*)((const char*)Wt + cur*16384
                                          + (hp*2 + h2)*2048 + m*128 + swzu);
            bf16x8 bfr[3];
#pragma unroll
            for (int fb = 0; fb < 3; ++fb)
                bfr[fb] = *(const bf16x8*)((const char*)vt_sh + cur*12288
                                           + (fh*48 + fb*16 + m)*128 + swzu);
#pragma unroll
            for (int h2 = 0; h2 < 2; ++h2)
#pragma unroll
                for (int fb = 0; fb < 3; ++fb)
                    acc[h2][fb] = __builtin_amdgcn_mfma_f32_16x16x32_bf16(
                        af[h2], bfr[fb], acc[h2][fb], 0, 0, 0);
        }

        if (c < 15) {
            {
                const int f = t >> 3, u = t & 7;
                *(uint4*)((char*)vt_sh + nxt*12288 + f*128 + ((u ^ (f & 7)) << 4)) = vr0;
            }
            if (t < 256) {
                const int e = t + 512, f2 = e >> 3, u2 = e & 7;
                *(uint4*)((char*)vt_sh + nxt*12288 + f2*128 + ((u2 ^ (f2 & 7)) << 4)) = vr1;
            }
        }
        if (c < 14) kT[cur][w][l] = kr;
        __syncthreads();
    }
#undef SMAX

    float s[4] = {0,0,0,0}, s2[4] = {0,0,0,0};
#pragma unroll
    for (int h2 = 0; h2 < 2; ++h2)
#pragma unroll
        for (int fb = 0; fb < 3; ++fb)
#pragma unroll
            for (int r = 0; r < 4; ++r) {
                const float v = acc[h2][fb][r];
                s[r] += v; s2[r] += v*v;
            }
#pragma unroll
    for (int msk = 1; msk < 16; msk <<= 1)
#pragma unroll
        for (int r = 0; r < 4; ++r) {
            s[r]  += __shfl_xor(s[r],  msk);
            s2[r] += __shfl_xor(s2[r], msk);
        }
    if (m == 0) {
#pragma unroll
        for (int r = 0; r < 4; ++r) { lnS[w][g*4+r] = s[r]; lnQ2[w][g*4+r] = s2[r]; }
    }

    const int rX = t >> 5, lX = t & 31;
    const size_t xrow = (size_t)(b*NN + i0 + rX);
    const float4* x4 = (const float4*)(X + xrow * F_IN);
    float4 xs[3];
    float sx = 0.f, sx2 = 0.f;
#pragma unroll
    for (int kk = 0; kk < 3; ++kk) {
        xs[kk] = x4[lX + 32*kk];
        sx  += xs[kk].x + xs[kk].y + xs[kk].z + xs[kk].w;
        sx2 += xs[kk].x*xs[kk].x + xs[kk].y*xs[kk].y + xs[kk].z*xs[kk].z + xs[kk].w*xs[kk].w;
    }
#pragma unroll
    for (int msk = 1; msk < 32; msk <<= 1) { sx += __shfl_xor(sx, msk); sx2 += __shfl_xor(sx2, msk); }
    if (lX == 0) { sxS[rX] = sx; sx2S[rX] = sx2; }
    __syncthreads();

    if (t < 16) {
        float tot = sxS[t], tot2 = sx2S[t];
#pragma unroll
        for (int ww = 0; ww < 8; ++ww) { tot += lnS[ww][t]; tot2 += lnQ2[ww][t]; }
        const float muh = tot * (1.f/H_DIM);
        const float varh = tot2 * (1.f/H_DIM) - muh*muh;
        mu_sh[t] = muh; rs_sh[t] = rsqrtf(varh + LN_EPS);
    }
    __syncthreads();

#pragma unroll
    for (int r = 0; r < 4; ++r) {
        const int row = g*4 + r;
        const size_t orow = (size_t)(b*NN + i0 + row);
        const float muh = mu_sh[row], rs = rs_sh[row];
#pragma unroll
        for (int h2 = 0; h2 < 2; ++h2)
#pragma unroll
            for (int fb = 0; fb < 3; ++fb) {
                const int col = (hp*2 + h2)*F_HID + fh*48 + fb*16 + m;
                const float v = acc[h2][fb][r];
                out[orow * OUT_DIM + F_OUT + col] = v;
                Hn[orow * H_DIM + col] = b16u((v - muh) * rs);
            }
    }
    {
        const float muh = mu_sh[rX], rs = rs_sh[rX];
        float4* oX = (float4*)(out + xrow * OUT_DIM + F_OUT + HEADS*F_HID);
#pragma unroll
        for (int kk = 0; kk < 3; ++kk) {
            oX[lX + 32*kk] = xs[kk];
            ushort4 hh;
            hh.x = b16u((xs[kk].x - muh) * rs);
            hh.y = b16u((xs[kk].y - muh) * rs);
            hh.z = b16u((xs[kk].z - muh) * rs);
            hh.w = b16u((xs[kk].w - muh) * rs);
            *(ushort4*)&Hn[xrow * H_DIM + HEADS*F_HID + 4*(lX + 32*kk)] = hh;
        }
    }
}

// ---------------- kC: O = lrelu(Hn @ WmT^T + bm), BM=64 BN=48, grid 1024 ----------
// 4 blocks/CU; wave w = i-sub [w*16, w*16+16), all 48 n-cols
__global__ __launch_bounds__(256) void kC(const unsigned short* __restrict__ Hn,
                                          const unsigned short* __restrict__ WmT,
                                          const float* __restrict__ bm,
                                          float* __restrict__ out) {
    __shared__ __align__(16) unsigned short As[2][64*64];   // 16 KB
    __shared__ __align__(16) unsigned short Bs[2][48*64];   // 12 KB
    const int t = threadIdx.x, w = t >> 6, lane = t & 63, m = lane & 15, g = lane >> 4;
    const int bid = (int)blockIdx.x;
    const int swz = (bid & 7) * 128 + (bid >> 3);   // bijective (1024%8==0)
    const int i0 = (swz >> 3) * 64;
    const int n0 = (swz & 7) * 48;

    const f32x4 z4 = {0.f, 0.f, 0.f, 0.f};
    f32x4 acc[3];
#pragma unroll
    for (int ns = 0; ns < 3; ++ns) acc[ns] = z4;

#define KC_STAGE(buf, k0)                                                              \
    {                                                                                  \
        _Pragma("unroll")                                                              \
        for (int p = 0; p < 2; ++p) {                                                  \
            const int e = t + 256*p, row = e >> 3, c16 = e & 7;                        \
            gl16(Hn + (size_t)(i0+row)*H_DIM + (k0) + ((c16 ^ (row&7)) << 3),          \
                 (char*)As[buf] + e*16);                                               \
        }                                                                              \
        {                                                                              \
            const int row = t >> 3, c16 = t & 7;                                       \
            gl16(WmT + (size_t)(n0+row)*H_DIM + (k0) + ((c16 ^ (row&7)) << 3),         \
                 (char*)Bs[buf] + t*16);                                               \
        }                                                                              \
        if (t < 128) {                                                                 \
            const int e = t + 256, row = e >> 3, c16 = e & 7;                          \
            gl16(WmT + (size_t)(n0+row)*H_DIM + (k0) + ((c16 ^ (row&7)) << 3),         \
                 (char*)Bs[buf] + e*16);                                               \
        }                                                                              \
    }

    KC_STAGE(0, 0);
    __syncthreads();

    for (int s = 0; s < 18; ++s) {
        const int cur = s & 1;
        if (s < 17) KC_STAGE(cur ^ 1, (s + 1) * 64);
#pragma unroll
        for (int kh = 0; kh < 2; ++kh) {
            const int kb = kh*64 + g*16;
            const int rowA = w*16 + m;
            const bf16x8 af = *(const bf16x8*)((const char*)As[cur] + rowA*128
                                               + (kb ^ ((rowA&7)<<4)));
#pragma unroll
            for (int ns = 0; ns < 3; ++ns) {
                const int row = ns*16 + m;
                const bf16x8 bf_ = *(const bf16x8*)((const char*)Bs[cur] + row*128
                                                    + (kb ^ ((row&7)<<4)));
                acc[ns] = __builtin_amdgcn_mfma_f32_16x16x32_bf16(af, bf_, acc[ns], 0, 0, 0);
            }
        }
        __syncthreads();
    }
#undef KC_STAGE

#pragma unroll
    for (int ns = 0; ns < 3; ++ns) {
        const int col = n0 + ns*16 + m;
        const float bmv = bm[col];
#pragma unroll
        for (int r = 0; r < 4; ++r) {
            float o = acc[ns][r] + bmv;
            o = fmaxf(o, NEG * o);
            out[(size_t)(i0 + w*16 + g*4 + r) * OUT_DIM + col] = o;
        }
    }
}

extern "C" void kernel_launch(void* const* d_in, const int* in_sizes, int n_in,
                              void* d_out, int out_size, void* d_ws, size_t ws_size,
                              hipStream_t stream) {
    const float* X  = (const float*)d_in[0];
    const float* Wv = (const float*)d_in[1];
    const float* bv = (const float*)d_in[2];
    const float* Wq = (const float*)d_in[3];
    const float* bq = (const float*)d_in[4];
    const float* Wk = (const float*)d_in[5];
    const float* bk = (const float*)d_in[6];
    const float* Wm = (const float*)d_in[7];
    const float* bm = (const float*)d_in[8];
    float* out = (float*)d_out;

    char* p = (char*)d_ws;
    unsigned short* VT  = (unsigned short*)p;                 p += (size_t)BB*F_HID*NN*2;
    float*          Qw  = (float*)p;                          p += (size_t)ROWS*HEADS*4;
    float*          Kw  = (float*)p;                          p += (size_t)ROWS*HEADS*4;
    unsigned short* WmT = (unsigned short*)p;                 p += (size_t)F_OUT*H_DIM*2;
    unsigned short* WvT = (unsigned short*)p;                 p += (size_t)F_HID*F_IN*2;
    unsigned short* Hn  = (unsigned short*)p;                 // ROWS*H_DIM*2 = 18 MB
    (void)ws_size; (void)out_size; (void)n_in; (void)in_sizes;

    kW<<<468, 256, 0, stream>>>(Wm, Wv, WmT, WvT);
    kA<<<ROWS/16, 384, 0, stream>>>(X, WvT, bv, Wq, bq, Wk, bk, VT, Qw, Kw);
    kB<<<BB*(NN/16), 512, 0, stream>>>(X, VT, Qw, Kw, out, Hn);
    kC<<<(ROWS/64)*(F_OUT/48), 256, 0, stream>>>(Hn, WmT, bm, out);
}